// Round 3
// baseline (266.822 us; speedup 1.0000x reference)
//
#include <hip/hip_runtime.h>

#define DM   768
#define QKVN 2304
#define SQ   512
#define NB   16
#define NH   12

typedef unsigned short u16;
typedef _Float16 h16;
typedef _Float16 h16x8 __attribute__((ext_vector_type(8)));
typedef float f32x4 __attribute__((ext_vector_type(4)));

__device__ __forceinline__ u16 f2h(float f) {
  h16 h = (h16)f;
  return __builtin_bit_cast(u16, h);
}
__device__ __forceinline__ float h2f(u16 u) {
  return (float)__builtin_bit_cast(h16, u);
}
__device__ __forceinline__ void gload_lds16(const void* g, void* l) {
  __builtin_amdgcn_global_load_lds((__attribute__((address_space(1))) void*)(g),
                                   (__attribute__((address_space(3))) void*)(l), 16, 0, 0);
}

// ---------------- all 8 weights f32 -> fp16, one launch ----------------
struct WPtrs { const float* s[8]; u16* d[8]; };
__global__ __launch_bounds__(256) void wconv8(WPtrs P) {
  int w = blockIdx.x / 576;
  int i = ((blockIdx.x % 576) * 256 + threadIdx.x) * 4;  // 576*256*4 == 589824 exactly
  float4 v = *reinterpret_cast<const float4*>(P.s[w] + i);
  ushort4 o;
  o.x = f2h(v.x); o.y = f2h(v.y); o.z = f2h(v.z); o.w = f2h(v.w);
  *reinterpret_cast<ushort4*>(P.d[w] + i) = o;
}

// ---------------- rope cos/sin table: tab[pos*64 + 2j]=cos, +1=sin ----------------
__global__ __launch_bounds__(256) void rope_tab_k(const float* __restrict__ invf, float* __restrict__ tab) {
  int i = blockIdx.x * 256 + threadIdx.x;   // 0..16383
  int pos = i >> 5, j = i & 31;
  float a = (float)pos * invf[j];
  float s, c;
  sincosf(a, &s, &c);
  tab[i * 2] = c; tab[i * 2 + 1] = s;
}

// ---------------- RMSNorm: one wave per token (768 f32 -> fp16) ----------------
__global__ __launch_bounds__(256) void rms_k(const float* __restrict__ x, const float* __restrict__ w,
                                             u16* __restrict__ out) {
  int wv = threadIdx.x >> 6, lane = threadIdx.x & 63;
  size_t t = (size_t)blockIdx.x * 4 + wv;
  const float* row = x + t * DM;
  float4 v[3];
  float ss = 0.f;
#pragma unroll
  for (int i = 0; i < 3; i++) {
    v[i] = *reinterpret_cast<const float4*>(row + (lane + 64 * i) * 4);
    ss += v[i].x * v[i].x + v[i].y * v[i].y + v[i].z * v[i].z + v[i].w * v[i].w;
  }
#pragma unroll
  for (int d = 1; d < 64; d <<= 1) ss += __shfl_xor(ss, d);
  float rs = rsqrtf(ss * (1.0f / 768.f) + 1e-6f);
  u16* orow = out + t * DM;
#pragma unroll
  for (int i = 0; i < 3; i++) {
    int c = (lane + 64 * i) * 4;
    float4 wv4 = *reinterpret_cast<const float4*>(w + c);
    ushort4 o;
    o.x = f2h(v[i].x * rs * wv4.x);
    o.y = f2h(v[i].y * rs * wv4.y);
    o.z = f2h(v[i].z * rs * wv4.z);
    o.w = f2h(v[i].w * rs * wv4.w);
    *reinterpret_cast<ushort4*>(orow + c) = o;
  }
}

// ---------------- GEMM: C[M=8192,N] = A[M,768] * W[N,768]^T (both fp16, K-major) ----------------
// 128x128 tile, BK=64, 4 waves (2x2), 16x16x32 MFMA. LDS linear + XOR-swizzled global source.
// ROPE: fused rotary on cols<1536 (QKV gemm of pass 1). PERM: 0=id, 1=row->(s*16+b), 2=row'->(b*512+s).
template <bool RESID, bool ROPE, int PERM>
__global__ __launch_bounds__(256) void gemm_k(const u16* __restrict__ A, const u16* __restrict__ W, int N,
                                              u16* __restrict__ Cb, float* __restrict__ Cf,
                                              const float* __restrict__ resid,
                                              const int* __restrict__ pids, const float* __restrict__ tab) {
  __shared__ u16 Al[128 * 64];
  __shared__ u16 Bl[128 * 64];
  const int tid = threadIdx.x, w = tid >> 6, lane = tid & 63;
  const int wr = w >> 1, wc = w & 1;
  const int bm = blockIdx.x, bnb = blockIdx.y;
  const int l15 = lane & 15, l4 = lane >> 4;
  f32x4 acc[4][4] = {};
  const int srow = lane >> 3;        // 0..7
  const int scol = (lane & 7) * 16;  // byte within 128B row chunk

  for (int kt = 0; kt < 12; ++kt) {
    __syncthreads();
#pragma unroll
    for (int e = 0; e < 4; e++) {
      int rr = w * 32 + e * 8;
      int r = rr + srow;
      int off = scol ^ ((r & 7) << 4);
      gload_lds16((const char*)A + (size_t)(bm * 128 + r) * 1536 + kt * 128 + off, (char*)Al + rr * 128);
      gload_lds16((const char*)W + (size_t)(bnb * 128 + r) * 1536 + kt * 128 + off, (char*)Bl + rr * 128);
    }
    __syncthreads();
#pragma unroll
    for (int kk = 0; kk < 2; kk++) {
      h16x8 am[4], bn[4];
#pragma unroll
      for (int i = 0; i < 4; i++) {
        int row = wr * 64 + i * 16 + l15;
        int off = (kk * 64 + 16 * l4) ^ ((row & 7) << 4);
        am[i] = *reinterpret_cast<const h16x8*>((const char*)Al + row * 128 + off);
      }
#pragma unroll
      for (int j = 0; j < 4; j++) {
        int row = wc * 64 + j * 16 + l15;
        int off = (kk * 64 + 16 * l4) ^ ((row & 7) << 4);
        bn[j] = *reinterpret_cast<const h16x8*>((const char*)Bl + row * 128 + off);
      }
#pragma unroll
      for (int i = 0; i < 4; i++)
#pragma unroll
        for (int j = 0; j < 4; j++)
          acc[i][j] = __builtin_amdgcn_mfma_f32_16x16x32_f16(am[i], bn[j], acc[i][j], 0, 0, 0);
    }
  }
  // fused RoPE: cols d=(col&63); partner (d, d+32) lives at (j, j+2). Q,K = bnb<12.
  if (ROPE && bnb < 12) {
#pragma unroll
    for (int i = 0; i < 4; i++) {
      int row0 = bm * 128 + wr * 64 + i * 16 + l4 * 4;
#pragma unroll
      for (int r = 0; r < 4; r++) {
        int pos = pids[row0 + r];
        const float* tb = tab + pos * 64;
#pragma unroll
        for (int j = 0; j < 2; j++) {
          float2 cs = *reinterpret_cast<const float2*>(tb + 2 * (j * 16 + l15));
          float x1 = acc[i][j][r], x2 = acc[i][j + 2][r];
          acc[i][j][r]     = x1 * cs.x - x2 * cs.y;
          acc[i][j + 2][r] = x2 * cs.x + x1 * cs.y;
        }
      }
    }
  }
#pragma unroll
  for (int i = 0; i < 4; i++) {
    int row0 = bm * 128 + wr * 64 + i * 16 + l4 * 4;
#pragma unroll
    for (int j = 0; j < 4; j++) {
      int col = bnb * 128 + wc * 64 + j * 16 + l15;
#pragma unroll
      for (int r = 0; r < 4; r++) {
        int rr = row0 + r;
        int orow = (PERM == 0) ? rr : (PERM == 1) ? ((rr & 511) * 16 + (rr >> 9))
                                                  : ((rr & 15) * 512 + (rr >> 4));
        size_t idx = (size_t)orow * N + col;
        float v = acc[i][j][r];
        if (RESID) Cf[idx] = v + resid[idx];
        else Cb[idx] = f2h(v);
      }
    }
  }
}

// ---------------- Pass-1 attention: causal flash over S, per (qtile, b, h) ----------------
// Analytic causal mask (input mask is exactly 0/-1e9 causal; exp underflows identically).
__global__ __launch_bounds__(256) void attn1_k(const u16* __restrict__ qkv, u16* __restrict__ O) {
  __shared__ u16 Kl[64 * 64];
  __shared__ u16 Vt[64 * 64];
  __shared__ u16 Pl[4][16 * 64];
  const int qt = blockIdx.x;   // 0..7
  const int bh = blockIdx.y;   // 0..191
  const int b = bh / NH, h = bh % NH;
  const int tid = threadIdx.x, w = tid >> 6, lane = tid & 63;
  const int l15 = lane & 15, l4 = lane >> 4;
  const size_t qoff = ((size_t)(b * SQ + qt * 64 + w * 16 + l15)) * QKVN + h * 64;
  h16x8 qf[2];
  qf[0] = *reinterpret_cast<const h16x8*>(qkv + qoff + 8 * l4);
  qf[1] = *reinterpret_cast<const h16x8*>(qkv + qoff + 32 + 8 * l4);
  f32x4 acco[4] = {};
  float mrun[4] = {-3e38f, -3e38f, -3e38f, -3e38f};
  float lrun[4] = {0.f, 0.f, 0.f, 0.f};
  const int qa0 = qt * 64 + w * 16 + l4 * 4;  // accumulator row base (q)

  for (int kt = 0; kt <= qt; ++kt) {
    __syncthreads();
#pragma unroll
    for (int e = 0; e < 2; e++) {
      int rr = (w * 2 + e) * 8;
      int r = rr + (lane >> 3);
      int off = ((lane & 7) * 16) ^ ((r & 7) << 4);
      gload_lds16((const char*)qkv + ((size_t)(b * SQ + kt * 64 + r) * QKVN + DM + h * 64) * 2 + off,
                  (char*)Kl + rr * 128);
    }
    {
      int key = tid >> 2, d0 = (tid & 3) * 16;
      const u16* vsrc = qkv + (size_t)(b * SQ + kt * 64 + key) * QKVN + 2 * DM + h * 64 + d0;
      ushort4 a0 = *reinterpret_cast<const ushort4*>(vsrc + 0);
      ushort4 a1 = *reinterpret_cast<const ushort4*>(vsrc + 4);
      ushort4 a2 = *reinterpret_cast<const ushort4*>(vsrc + 8);
      ushort4 a3 = *reinterpret_cast<const ushort4*>(vsrc + 12);
      u16 vals[16] = {a0.x, a0.y, a0.z, a0.w, a1.x, a1.y, a1.z, a1.w,
                      a2.x, a2.y, a2.z, a2.w, a3.x, a3.y, a3.z, a3.w};
#pragma unroll
      for (int i = 0; i < 16; i++) {
        int d = d0 + i;
        int byte = d * 128 + ((2 * key) ^ ((d & 7) << 4));
        *(u16*)((char*)Vt + byte) = vals[i];
      }
    }
    __syncthreads();
    f32x4 sc[4] = {};
#pragma unroll
    for (int kk = 0; kk < 2; kk++) {
#pragma unroll
      for (int j = 0; j < 4; j++) {
        int row = j * 16 + l15;
        int off = (kk * 64 + 16 * l4) ^ ((row & 7) << 4);
        h16x8 kf = *reinterpret_cast<const h16x8*>((const char*)Kl + row * 128 + off);
        sc[j] = __builtin_amdgcn_mfma_f32_16x16x32_f16(qf[kk], kf, sc[j], 0, 0, 0);
      }
    }
    float pv[4][4];
#pragma unroll
    for (int r = 0; r < 4; r++)
#pragma unroll
      for (int j = 0; j < 4; j++) pv[j][r] = sc[j][r];
    if (kt == qt) {  // diagonal tile: per-element causal
#pragma unroll
      for (int r = 0; r < 4; r++) {
        int q = qa0 + r;
#pragma unroll
        for (int j = 0; j < 4; j++) {
          int key = kt * 64 + j * 16 + l15;
          if (key > q) pv[j][r] = -1e30f;
        }
      }
    }
    float al[4];
#pragma unroll
    for (int r = 0; r < 4; r++) {
      float tm = fmaxf(fmaxf(pv[0][r], pv[1][r]), fmaxf(pv[2][r], pv[3][r]));
      tm = fmaxf(tm, __shfl_xor(tm, 1)); tm = fmaxf(tm, __shfl_xor(tm, 2));
      tm = fmaxf(tm, __shfl_xor(tm, 4)); tm = fmaxf(tm, __shfl_xor(tm, 8));
      float mn = fmaxf(mrun[r], tm);
      al[r] = __expf(mrun[r] - mn);
      mrun[r] = mn;
      float ts = 0.f;
#pragma unroll
      for (int j = 0; j < 4; j++) { float p = __expf(pv[j][r] - mn); pv[j][r] = p; ts += p; }
      ts += __shfl_xor(ts, 1); ts += __shfl_xor(ts, 2); ts += __shfl_xor(ts, 4); ts += __shfl_xor(ts, 8);
      lrun[r] = lrun[r] * al[r] + ts;
    }
#pragma unroll
    for (int j = 0; j < 4; j++)
#pragma unroll
      for (int r = 0; r < 4; r++) acco[j][r] *= al[r];
    u16* pw = Pl[w];
#pragma unroll
    for (int r = 0; r < 4; r++) {
      int q = l4 * 4 + r;
      int sw = (q & 7) << 4;
#pragma unroll
      for (int j = 0; j < 4; j++) {
        int byte = q * 128 + ((2 * (j * 16 + l15)) ^ sw);
        *(u16*)((char*)pw + byte) = f2h(pv[j][r]);
      }
    }
    asm volatile("s_waitcnt lgkmcnt(0)" ::: "memory");
    __builtin_amdgcn_sched_barrier(0);
#pragma unroll
    for (int kk = 0; kk < 2; kk++) {
      int poff = (kk * 64 + 16 * l4) ^ ((l15 & 7) << 4);
      h16x8 pa = *reinterpret_cast<const h16x8*>((const char*)pw + l15 * 128 + poff);
#pragma unroll
      for (int j = 0; j < 4; j++) {
        int d = j * 16 + l15;
        int voff = (kk * 64 + 16 * l4) ^ ((d & 7) << 4);
        h16x8 vf = *reinterpret_cast<const h16x8*>((const char*)Vt + d * 128 + voff);
        acco[j] = __builtin_amdgcn_mfma_f32_16x16x32_f16(pa, vf, acco[j], 0, 0, 0);
      }
    }
  }
#pragma unroll
  for (int r = 0; r < 4; r++) {
    float inv = 1.f / lrun[r];
    size_t orow = ((size_t)(b * SQ + qa0 + r)) * DM + h * 64;
#pragma unroll
    for (int j = 0; j < 4; j++) O[orow + j * 16 + l15] = f2h(acco[j][r] * inv);
  }
}

// ---------------- Pass-2 attention: 16x16 per (s,h), one wave each (s-major qkv) ----------------
__global__ __launch_bounds__(256) void attn2_k(const u16* __restrict__ qkv, const float* __restrict__ gmask,
                                               u16* __restrict__ O) {
  __shared__ float Pl[4][16][16];
  __shared__ float Vl[4][16][68];
  const int tid = threadIdx.x, w = tid >> 6, lane = tid & 63;
  const int idx = blockIdx.x * 4 + w;
  const int s = idx / NH, h = idx % NH;
  const int l15 = lane & 15, l4 = lane >> 4;
  // rows s*16 + b are contiguous (s-major layout from PERM=1 gemm)
  const size_t base = ((size_t)(s * 16 + l15)) * QKVN + h * 64;
  h16x8 qf0 = *reinterpret_cast<const h16x8*>(qkv + base + 8 * l4);
  h16x8 qf1 = *reinterpret_cast<const h16x8*>(qkv + base + 32 + 8 * l4);
  h16x8 kf0 = *reinterpret_cast<const h16x8*>(qkv + base + DM + 8 * l4);
  h16x8 kf1 = *reinterpret_cast<const h16x8*>(qkv + base + DM + 32 + 8 * l4);
  f32x4 sc = {};
  sc = __builtin_amdgcn_mfma_f32_16x16x32_f16(qf0, kf0, sc, 0, 0, 0);
  sc = __builtin_amdgcn_mfma_f32_16x16x32_f16(qf1, kf1, sc, 0, 0, 0);
  {
    int key = lane >> 2, d0 = (lane & 3) * 16;
    const u16* vsrc = qkv + ((size_t)(s * 16 + key)) * QKVN + 2 * DM + h * 64 + d0;
#pragma unroll
    for (int i = 0; i < 16; i += 4) {
      ushort4 vv = *reinterpret_cast<const ushort4*>(vsrc + i);
      Vl[w][key][d0 + i + 0] = h2f(vv.x);
      Vl[w][key][d0 + i + 1] = h2f(vv.y);
      Vl[w][key][d0 + i + 2] = h2f(vv.z);
      Vl[w][key][d0 + i + 3] = h2f(vv.w);
    }
  }
  const float* gm = gmask + ((size_t)s * NH + h) * 256;
#pragma unroll
  for (int r = 0; r < 4; r++) {
    float v = sc[r] + gm[(l4 * 4 + r) * 16 + l15];
    float mx = v;
    mx = fmaxf(mx, __shfl_xor(mx, 1)); mx = fmaxf(mx, __shfl_xor(mx, 2));
    mx = fmaxf(mx, __shfl_xor(mx, 4)); mx = fmaxf(mx, __shfl_xor(mx, 8));
    float p = __expf(v - mx);
    float su = p;
    su += __shfl_xor(su, 1); su += __shfl_xor(su, 2); su += __shfl_xor(su, 4); su += __shfl_xor(su, 8);
    Pl[w][l4 * 4 + r][l15] = p / su;
  }
  asm volatile("s_waitcnt lgkmcnt(0)" ::: "memory");
  __builtin_amdgcn_sched_barrier(0);
  const int q = lane >> 2, d0 = (lane & 3) * 16;
  float o[16] = {};
#pragma unroll
  for (int key = 0; key < 16; key++) {
    float pp = Pl[w][q][key];
#pragma unroll
    for (int dd = 0; dd < 16; dd += 4) {
      float4 vv = *reinterpret_cast<const float4*>(&Vl[w][key][d0 + dd]);
      o[dd + 0] += pp * vv.x; o[dd + 1] += pp * vv.y; o[dd + 2] += pp * vv.z; o[dd + 3] += pp * vv.w;
    }
  }
  // write s-major: row = s*16 + q
  u16* orow = O + ((size_t)(s * 16 + q)) * DM + h * 64 + d0;
#pragma unroll
  for (int i = 0; i < 16; i += 4) {
    ushort4 ov;
    ov.x = f2h(o[i]); ov.y = f2h(o[i + 1]); ov.z = f2h(o[i + 2]); ov.w = f2h(o[i + 3]);
    *reinterpret_cast<ushort4*>(orow + i) = ov;
  }
}

// ---------------- launch ----------------
extern "C" void kernel_launch(void* const* d_in, const int* in_sizes, int n_in,
                              void* d_out, int out_size, void* d_ws, size_t ws_size,
                              hipStream_t stream) {
  const float* hidden = (const float*)d_in[0];
  const int*   pids   = (const int*)d_in[1];
  const float* gmask  = (const float*)d_in[3];
  const float* tq = (const float*)d_in[4];
  const float* tk = (const float*)d_in[5];
  const float* tv = (const float*)d_in[6];
  const float* to_ = (const float*)d_in[7];
  const float* tnw = (const float*)d_in[8];
  const float* gq = (const float*)d_in[9];
  const float* gk = (const float*)d_in[10];
  const float* gv = (const float*)d_in[11];
  const float* go = (const float*)d_in[12];
  const float* gnw = (const float*)d_in[13];
  const float* invf = (const float*)d_in[14];
  float* out = (float*)d_out;
  char* ws = (char*)d_ws;

  u16*   wq1    = (u16*)(ws);                   // 2304x768 fp16
  u16*   wo1    = (u16*)(ws + 3538944);         // 768x768
  u16*   wq2    = (u16*)(ws + 4718592);
  u16*   wo2    = (u16*)(ws + 8257536);
  float* tab    = (float*)(ws + 9437184);       // 512x32x2 f32
  u16*   normed = (u16*)(ws + 9568256);         // 8192x768 fp16
  u16*   obuf   = (u16*)(ws + 22151168);        // 8192x768 fp16
  float* h1     = (float*)(ws + 34734080);      // 8192x768 f32
  u16*   qkv    = (u16*)(ws + 59899904);        // 8192x2304 fp16

  const int WN = 768 * 768;
  WPtrs P;
  P.s[0] = tq;  P.d[0] = wq1;
  P.s[1] = tk;  P.d[1] = wq1 + WN;
  P.s[2] = tv;  P.d[2] = wq1 + 2 * WN;
  P.s[3] = to_; P.d[3] = wo1;
  P.s[4] = gq;  P.d[4] = wq2;
  P.s[5] = gk;  P.d[5] = wq2 + WN;
  P.s[6] = gv;  P.d[6] = wq2 + 2 * WN;
  P.s[7] = go;  P.d[7] = wo2;
  wconv8<<<4608, 256, 0, stream>>>(P);
  rope_tab_k<<<64, 256, 0, stream>>>(invf, tab);

  // pass 1 (time attention, causal + fused RoPE)
  rms_k<<<2048, 256, 0, stream>>>(hidden, tnw, normed);
  gemm_k<false, true, 0><<<dim3(64, 18), 256, 0, stream>>>(normed, wq1, QKVN, qkv, nullptr, nullptr, pids, tab);
  attn1_k<<<dim3(8, 192), 256, 0, stream>>>(qkv, obuf);
  gemm_k<true, false, 0><<<dim3(64, 6), 256, 0, stream>>>(obuf, wo1, DM, nullptr, h1, hidden, nullptr, nullptr);

  // pass 2 (group attention over batch dim; s-major token order)
  rms_k<<<2048, 256, 0, stream>>>(h1, gnw, normed);
  gemm_k<false, false, 1><<<dim3(64, 18), 256, 0, stream>>>(normed, wq2, QKVN, qkv, nullptr, nullptr, nullptr, nullptr);
  attn2_k<<<1536, 256, 0, stream>>>(qkv, gmask, obuf);
  gemm_k<true, false, 2><<<dim3(64, 6), 256, 0, stream>>>(obuf, wo2, DM, nullptr, out, h1, nullptr, nullptr);
}

// Round 4
// 250.025 us; speedup vs baseline: 1.0672x; 1.0672x over previous
//
#include <hip/hip_runtime.h>

#define DM   768
#define QKVN 2304
#define SQ   512
#define NB   16
#define NH   12

typedef unsigned short u16;
typedef _Float16 h16;
typedef _Float16 h16x8 __attribute__((ext_vector_type(8)));
typedef float f32x4 __attribute__((ext_vector_type(4)));

__device__ __forceinline__ u16 f2h(float f) {
  h16 h = (h16)f;
  return __builtin_bit_cast(u16, h);
}
__device__ __forceinline__ float h2f(u16 u) {
  return (float)__builtin_bit_cast(h16, u);
}
__device__ __forceinline__ void gload_lds16(const void* g, void* l) {
  __builtin_amdgcn_global_load_lds((__attribute__((address_space(1))) void*)(g),
                                   (__attribute__((address_space(3))) void*)(l), 16, 0, 0);
}

// ---------------- all 8 weights f32 -> fp16, one launch ----------------
struct WPtrs { const float* s[8]; u16* d[8]; };
__global__ __launch_bounds__(256) void wconv8(WPtrs P) {
  int w = blockIdx.x / 576;
  int i = ((blockIdx.x % 576) * 256 + threadIdx.x) * 4;  // 576*256*4 == 589824 exactly
  float4 v = *reinterpret_cast<const float4*>(P.s[w] + i);
  ushort4 o;
  o.x = f2h(v.x); o.y = f2h(v.y); o.z = f2h(v.z); o.w = f2h(v.w);
  *reinterpret_cast<ushort4*>(P.d[w] + i) = o;
}

// ---------------- rope cos/sin table: tab[pos*64 + 2j]=cos, +1=sin ----------------
__global__ __launch_bounds__(256) void rope_tab_k(const float* __restrict__ invf, float* __restrict__ tab) {
  int i = blockIdx.x * 256 + threadIdx.x;   // 0..16383
  int pos = i >> 5, j = i & 31;
  float a = (float)pos * invf[j];
  float s, c;
  sincosf(a, &s, &c);
  tab[i * 2] = c; tab[i * 2 + 1] = s;
}

// ---------------- RMSNorm: one wave per token (768 f32 -> fp16) ----------------
__global__ __launch_bounds__(256) void rms_k(const float* __restrict__ x, const float* __restrict__ w,
                                             u16* __restrict__ out) {
  int wv = threadIdx.x >> 6, lane = threadIdx.x & 63;
  size_t t = (size_t)blockIdx.x * 4 + wv;
  const float* row = x + t * DM;
  float4 v[3];
  float ss = 0.f;
#pragma unroll
  for (int i = 0; i < 3; i++) {
    v[i] = *reinterpret_cast<const float4*>(row + (lane + 64 * i) * 4);
    ss += v[i].x * v[i].x + v[i].y * v[i].y + v[i].z * v[i].z + v[i].w * v[i].w;
  }
#pragma unroll
  for (int d = 1; d < 64; d <<= 1) ss += __shfl_xor(ss, d);
  float rs = rsqrtf(ss * (1.0f / 768.f) + 1e-6f);
  u16* orow = out + t * DM;
#pragma unroll
  for (int i = 0; i < 3; i++) {
    int c = (lane + 64 * i) * 4;
    float4 wv4 = *reinterpret_cast<const float4*>(w + c);
    ushort4 o;
    o.x = f2h(v[i].x * rs * wv4.x);
    o.y = f2h(v[i].y * rs * wv4.y);
    o.z = f2h(v[i].z * rs * wv4.z);
    o.w = f2h(v[i].w * rs * wv4.w);
    *reinterpret_cast<ushort4*>(orow + c) = o;
  }
}

// ---------------- GEMM: C[M=8192,N] = A[M,768] * W[N,768]^T (both fp16, K-major) ----------------
// 128x128 tile, BK=32, 4 waves (2x2), 16x16x32 MFMA.
// 4-deep LDS buffers + counted vmcnt(8) pipeline (T3+T4), setprio around MFMA (T5),
// bijective XCD swizzle (grids are %8==0). Swizzle: 16B-chunk k4 ^= (row>>1)&3 (2-way banks, free).
// Buffer (t+3)&3 is dead when staged at tile t: its last reader (tile t-1) drained at t-1's barrier.
// vmcnt(8) leaves stages of tiles t+2,t+3 outstanding => tile t+1 landed before its reads.
template <bool RESID, bool ROPE, int PERM>
__global__ __launch_bounds__(256, 2) void gemm_k(const u16* __restrict__ A, const u16* __restrict__ W, int N,
                                              u16* __restrict__ Cb, float* __restrict__ Cf,
                                              const float* __restrict__ resid,
                                              const int* __restrict__ pids, const float* __restrict__ tab) {
  __shared__ __align__(16) char L[4 * 16384];   // 4 bufs x (A 8KB + B 8KB)
  const int tid = threadIdx.x, w = tid >> 6, lane = tid & 63;
  const int wr = w >> 1, wc = w & 1;
  // bijective XCD swizzle (nwg % 8 == 0 for all our grids; gridDim.x == 64)
  int nf = blockIdx.y * gridDim.x + blockIdx.x;
  int nwg = gridDim.x * gridDim.y;
  int swv = (nf & 7) * (nwg >> 3) + (nf >> 3);
  const int bm = swv & 63;
  const int bnb = swv >> 6;
  const int l15 = lane & 15, l4 = lane >> 4;
  f32x4 acc[4][4] = {};

  // stage addressing: A/B tile = 128 rows x 32 k fp16 (64 B rows, 4x16B chunks).
  // chunks c0 = tid (rows 0..63), c1 = tid+256 (rows 64..127); k4s = k4 ^ ((r>>1)&3).
  const int r0 = tid >> 2, k40 = tid & 3;
  const int k4s = k40 ^ ((r0 >> 1) & 3);      // (r0+64)>>1 has same &3 => shared
  const size_t aA0 = (size_t)(bm * 128 + r0) * 1536 + k4s * 16;
  const size_t aA1 = (size_t)(bm * 128 + r0 + 64) * 1536 + k4s * 16;
  const size_t aB0 = (size_t)(bnb * 128 + r0) * 1536 + k4s * 16;
  const size_t aB1 = (size_t)(bnb * 128 + r0 + 64) * 1536 + k4s * 16;
  const int dc0 = tid * 16, dc1 = dc0 + 4096;
  const char* Ab = (const char*)A;
  const char* Wb = (const char*)W;

#define STAGE(T64, Q) do { \
    gload_lds16(Ab + aA0 + (T64), L + (Q) * 16384 + dc0); \
    gload_lds16(Ab + aA1 + (T64), L + (Q) * 16384 + dc1); \
    gload_lds16(Wb + aB0 + (T64), L + (Q) * 16384 + 8192 + dc0); \
    gload_lds16(Wb + aB1 + (T64), L + (Q) * 16384 + 8192 + dc1); \
  } while (0)

  // per-thread ds_read byte offsets (within a buffer)
  int obA[4], obB[4];
#pragma unroll
  for (int i = 0; i < 4; i++) {
    int rowA = wr * 64 + i * 16 + l15;
    obA[i] = rowA * 64 + ((l4 ^ ((rowA >> 1) & 3)) * 16);
    int rowB = wc * 64 + i * 16 + l15;
    obB[i] = 8192 + rowB * 64 + ((l4 ^ ((rowB >> 1) & 3)) * 16);
  }

  // prologue: stage tiles 0,1,2
  STAGE(0, 0); STAGE(64, 1); STAGE(128, 2);
  asm volatile("s_waitcnt vmcnt(8)" ::: "memory");
  __builtin_amdgcn_sched_barrier(0);
  __builtin_amdgcn_s_barrier();
  __builtin_amdgcn_sched_barrier(0);

#pragma unroll
  for (int to = 0; to < 6; ++to) {
#pragma unroll
    for (int ti = 0; ti < 4; ++ti) {
      const int t = to * 4 + ti;
      const int tn = (t + 3 < 24) ? (t + 3) : 23;     // tail: dummy re-stage of tile 23
      STAGE(tn * 64, (t + 3) & 3);                    // dest buffer is provably dead
      const char* bq = L + (t & 3) * 16384;
      h16x8 am[4], bn[4];
#pragma unroll
      for (int i = 0; i < 4; i++) am[i] = *reinterpret_cast<const h16x8*>(bq + obA[i]);
#pragma unroll
      for (int j = 0; j < 4; j++) bn[j] = *reinterpret_cast<const h16x8*>(bq + obB[j]);
      __builtin_amdgcn_s_setprio(1);
#pragma unroll
      for (int i = 0; i < 4; i++)
#pragma unroll
        for (int j = 0; j < 4; j++)
          acc[i][j] = __builtin_amdgcn_mfma_f32_16x16x32_f16(am[i], bn[j], acc[i][j], 0, 0, 0);
      __builtin_amdgcn_s_setprio(0);
      asm volatile("s_waitcnt vmcnt(8)" ::: "memory");
      __builtin_amdgcn_sched_barrier(0);
      __builtin_amdgcn_s_barrier();
      __builtin_amdgcn_sched_barrier(0);
    }
  }
#undef STAGE
  asm volatile("s_waitcnt vmcnt(0)" ::: "memory");   // drain dummy stages before exit

  // fused RoPE: cols d=(col&63); partner (d, d+32) lives at (j, j+2). Q,K = bnb<12.
  if (ROPE && bnb < 12) {
#pragma unroll
    for (int i = 0; i < 4; i++) {
      int row0 = bm * 128 + wr * 64 + i * 16 + l4 * 4;
#pragma unroll
      for (int r = 0; r < 4; r++) {
        int pos = pids[row0 + r];
        const float* tb = tab + pos * 64;
#pragma unroll
        for (int j = 0; j < 2; j++) {
          float2 cs = *reinterpret_cast<const float2*>(tb + 2 * (j * 16 + l15));
          float x1 = acc[i][j][r], x2 = acc[i][j + 2][r];
          acc[i][j][r]     = x1 * cs.x - x2 * cs.y;
          acc[i][j + 2][r] = x2 * cs.x + x1 * cs.y;
        }
      }
    }
  }
#pragma unroll
  for (int i = 0; i < 4; i++) {
    int row0 = bm * 128 + wr * 64 + i * 16 + l4 * 4;
#pragma unroll
    for (int j = 0; j < 4; j++) {
      int col = bnb * 128 + wc * 64 + j * 16 + l15;
#pragma unroll
      for (int r = 0; r < 4; r++) {
        int rr = row0 + r;
        int orow = (PERM == 0) ? rr : (PERM == 1) ? ((rr & 511) * 16 + (rr >> 9))
                                                  : ((rr & 15) * 512 + (rr >> 4));
        size_t idx = (size_t)orow * N + col;
        float v = acc[i][j][r];
        if (RESID) Cf[idx] = v + resid[idx];
        else Cb[idx] = f2h(v);
      }
    }
  }
}

// ---------------- Pass-1 attention: causal flash over S, per (qtile, b, h) ----------------
// Analytic causal mask (input mask is exactly 0/-1e9 causal; exp underflows identically).
__global__ __launch_bounds__(256) void attn1_k(const u16* __restrict__ qkv, u16* __restrict__ O) {
  __shared__ u16 Kl[64 * 64];
  __shared__ u16 Vt[64 * 64];
  __shared__ u16 Pl[4][16 * 64];
  const int qt = blockIdx.x;   // 0..7
  const int bh = blockIdx.y;   // 0..191
  const int b = bh / NH, h = bh % NH;
  const int tid = threadIdx.x, w = tid >> 6, lane = tid & 63;
  const int l15 = lane & 15, l4 = lane >> 4;
  const size_t qoff = ((size_t)(b * SQ + qt * 64 + w * 16 + l15)) * QKVN + h * 64;
  h16x8 qf[2];
  qf[0] = *reinterpret_cast<const h16x8*>(qkv + qoff + 8 * l4);
  qf[1] = *reinterpret_cast<const h16x8*>(qkv + qoff + 32 + 8 * l4);
  f32x4 acco[4] = {};
  float mrun[4] = {-3e38f, -3e38f, -3e38f, -3e38f};
  float lrun[4] = {0.f, 0.f, 0.f, 0.f};
  const int qa0 = qt * 64 + w * 16 + l4 * 4;  // accumulator row base (q)

  for (int kt = 0; kt <= qt; ++kt) {
    __syncthreads();
#pragma unroll
    for (int e = 0; e < 2; e++) {
      int rr = (w * 2 + e) * 8;
      int r = rr + (lane >> 3);
      int off = ((lane & 7) * 16) ^ ((r & 7) << 4);
      gload_lds16((const char*)qkv + ((size_t)(b * SQ + kt * 64 + r) * QKVN + DM + h * 64) * 2 + off,
                  (char*)Kl + rr * 128);
    }
    {
      int key = tid >> 2, d0 = (tid & 3) * 16;
      const u16* vsrc = qkv + (size_t)(b * SQ + kt * 64 + key) * QKVN + 2 * DM + h * 64 + d0;
      ushort4 a0 = *reinterpret_cast<const ushort4*>(vsrc + 0);
      ushort4 a1 = *reinterpret_cast<const ushort4*>(vsrc + 4);
      ushort4 a2 = *reinterpret_cast<const ushort4*>(vsrc + 8);
      ushort4 a3 = *reinterpret_cast<const ushort4*>(vsrc + 12);
      u16 vals[16] = {a0.x, a0.y, a0.z, a0.w, a1.x, a1.y, a1.z, a1.w,
                      a2.x, a2.y, a2.z, a2.w, a3.x, a3.y, a3.z, a3.w};
#pragma unroll
      for (int i = 0; i < 16; i++) {
        int d = d0 + i;
        int byte = d * 128 + ((2 * key) ^ ((d & 7) << 4));
        *(u16*)((char*)Vt + byte) = vals[i];
      }
    }
    __syncthreads();
    f32x4 sc[4] = {};
#pragma unroll
    for (int kk = 0; kk < 2; kk++) {
#pragma unroll
      for (int j = 0; j < 4; j++) {
        int row = j * 16 + l15;
        int off = (kk * 64 + 16 * l4) ^ ((row & 7) << 4);
        h16x8 kf = *reinterpret_cast<const h16x8*>((const char*)Kl + row * 128 + off);
        sc[j] = __builtin_amdgcn_mfma_f32_16x16x32_f16(qf[kk], kf, sc[j], 0, 0, 0);
      }
    }
    float pv[4][4];
#pragma unroll
    for (int r = 0; r < 4; r++)
#pragma unroll
      for (int j = 0; j < 4; j++) pv[j][r] = sc[j][r];
    if (kt == qt) {  // diagonal tile: per-element causal
#pragma unroll
      for (int r = 0; r < 4; r++) {
        int q = qa0 + r;
#pragma unroll
        for (int j = 0; j < 4; j++) {
          int key = kt * 64 + j * 16 + l15;
          if (key > q) pv[j][r] = -1e30f;
        }
      }
    }
    float al[4];
#pragma unroll
    for (int r = 0; r < 4; r++) {
      float tm = fmaxf(fmaxf(pv[0][r], pv[1][r]), fmaxf(pv[2][r], pv[3][r]));
      tm = fmaxf(tm, __shfl_xor(tm, 1)); tm = fmaxf(tm, __shfl_xor(tm, 2));
      tm = fmaxf(tm, __shfl_xor(tm, 4)); tm = fmaxf(tm, __shfl_xor(tm, 8));
      float mn = fmaxf(mrun[r], tm);
      al[r] = __expf(mrun[r] - mn);
      mrun[r] = mn;
      float ts = 0.f;
#pragma unroll
      for (int j = 0; j < 4; j++) { float p = __expf(pv[j][r] - mn); pv[j][r] = p; ts += p; }
      ts += __shfl_xor(ts, 1); ts += __shfl_xor(ts, 2); ts += __shfl_xor(ts, 4); ts += __shfl_xor(ts, 8);
      lrun[r] = lrun[r] * al[r] + ts;
    }
#pragma unroll
    for (int j = 0; j < 4; j++)
#pragma unroll
      for (int r = 0; r < 4; r++) acco[j][r] *= al[r];
    u16* pw = Pl[w];
#pragma unroll
    for (int r = 0; r < 4; r++) {
      int q = l4 * 4 + r;
      int sw = (q & 7) << 4;
#pragma unroll
      for (int j = 0; j < 4; j++) {
        int byte = q * 128 + ((2 * (j * 16 + l15)) ^ sw);
        *(u16*)((char*)pw + byte) = f2h(pv[j][r]);
      }
    }
    asm volatile("s_waitcnt lgkmcnt(0)" ::: "memory");
    __builtin_amdgcn_sched_barrier(0);
#pragma unroll
    for (int kk = 0; kk < 2; kk++) {
      int poff = (kk * 64 + 16 * l4) ^ ((l15 & 7) << 4);
      h16x8 pa = *reinterpret_cast<const h16x8*>((const char*)pw + l15 * 128 + poff);
#pragma unroll
      for (int j = 0; j < 4; j++) {
        int d = j * 16 + l15;
        int voff = (kk * 64 + 16 * l4) ^ ((d & 7) << 4);
        h16x8 vf = *reinterpret_cast<const h16x8*>((const char*)Vt + d * 128 + voff);
        acco[j] = __builtin_amdgcn_mfma_f32_16x16x32_f16(pa, vf, acco[j], 0, 0, 0);
      }
    }
  }
#pragma unroll
  for (int r = 0; r < 4; r++) {
    float inv = 1.f / lrun[r];
    size_t orow = ((size_t)(b * SQ + qa0 + r)) * DM + h * 64;
#pragma unroll
    for (int j = 0; j < 4; j++) O[orow + j * 16 + l15] = f2h(acco[j][r] * inv);
  }
}

// ---------------- Pass-2 attention: 16x16 per (s,h), one wave each (s-major qkv) ----------------
__global__ __launch_bounds__(256) void attn2_k(const u16* __restrict__ qkv, const float* __restrict__ gmask,
                                               u16* __restrict__ O) {
  __shared__ float Pl[4][16][16];
  __shared__ float Vl[4][16][68];
  const int tid = threadIdx.x, w = tid >> 6, lane = tid & 63;
  const int idx = blockIdx.x * 4 + w;
  const int s = idx / NH, h = idx % NH;
  const int l15 = lane & 15, l4 = lane >> 4;
  // rows s*16 + b are contiguous (s-major layout from PERM=1 gemm)
  const size_t base = ((size_t)(s * 16 + l15)) * QKVN + h * 64;
  h16x8 qf0 = *reinterpret_cast<const h16x8*>(qkv + base + 8 * l4);
  h16x8 qf1 = *reinterpret_cast<const h16x8*>(qkv + base + 32 + 8 * l4);
  h16x8 kf0 = *reinterpret_cast<const h16x8*>(qkv + base + DM + 8 * l4);
  h16x8 kf1 = *reinterpret_cast<const h16x8*>(qkv + base + DM + 32 + 8 * l4);
  f32x4 sc = {};
  sc = __builtin_amdgcn_mfma_f32_16x16x32_f16(qf0, kf0, sc, 0, 0, 0);
  sc = __builtin_amdgcn_mfma_f32_16x16x32_f16(qf1, kf1, sc, 0, 0, 0);
  {
    int key = lane >> 2, d0 = (lane & 3) * 16;
    const u16* vsrc = qkv + ((size_t)(s * 16 + key)) * QKVN + 2 * DM + h * 64 + d0;
#pragma unroll
    for (int i = 0; i < 16; i += 4) {
      ushort4 vv = *reinterpret_cast<const ushort4*>(vsrc + i);
      Vl[w][key][d0 + i + 0] = h2f(vv.x);
      Vl[w][key][d0 + i + 1] = h2f(vv.y);
      Vl[w][key][d0 + i + 2] = h2f(vv.z);
      Vl[w][key][d0 + i + 3] = h2f(vv.w);
    }
  }
  const float* gm = gmask + ((size_t)s * NH + h) * 256;
#pragma unroll
  for (int r = 0; r < 4; r++) {
    float v = sc[r] + gm[(l4 * 4 + r) * 16 + l15];
    float mx = v;
    mx = fmaxf(mx, __shfl_xor(mx, 1)); mx = fmaxf(mx, __shfl_xor(mx, 2));
    mx = fmaxf(mx, __shfl_xor(mx, 4)); mx = fmaxf(mx, __shfl_xor(mx, 8));
    float p = __expf(v - mx);
    float su = p;
    su += __shfl_xor(su, 1); su += __shfl_xor(su, 2); su += __shfl_xor(su, 4); su += __shfl_xor(su, 8);
    Pl[w][l4 * 4 + r][l15] = p / su;
  }
  asm volatile("s_waitcnt lgkmcnt(0)" ::: "memory");
  __builtin_amdgcn_sched_barrier(0);
  const int q = lane >> 2, d0 = (lane & 3) * 16;
  float o[16] = {};
#pragma unroll
  for (int key = 0; key < 16; key++) {
    float pp = Pl[w][q][key];
#pragma unroll
    for (int dd = 0; dd < 16; dd += 4) {
      float4 vv = *reinterpret_cast<const float4*>(&Vl[w][key][d0 + dd]);
      o[dd + 0] += pp * vv.x; o[dd + 1] += pp * vv.y; o[dd + 2] += pp * vv.z; o[dd + 3] += pp * vv.w;
    }
  }
  // write s-major: row = s*16 + q
  u16* orow = O + ((size_t)(s * 16 + q)) * DM + h * 64 + d0;
#pragma unroll
  for (int i = 0; i < 16; i += 4) {
    ushort4 ov;
    ov.x = f2h(o[i]); ov.y = f2h(o[i + 1]); ov.z = f2h(o[i + 2]); ov.w = f2h(o[i + 3]);
    *reinterpret_cast<ushort4*>(orow + i) = ov;
  }
}

// ---------------- launch ----------------
extern "C" void kernel_launch(void* const* d_in, const int* in_sizes, int n_in,
                              void* d_out, int out_size, void* d_ws, size_t ws_size,
                              hipStream_t stream) {
  const float* hidden = (const float*)d_in[0];
  const int*   pids   = (const int*)d_in[1];
  const float* gmask  = (const float*)d_in[3];
  const float* tq = (const float*)d_in[4];
  const float* tk = (const float*)d_in[5];
  const float* tv = (const float*)d_in[6];
  const float* to_ = (const float*)d_in[7];
  const float* tnw = (const float*)d_in[8];
  const float* gq = (const float*)d_in[9];
  const float* gk = (const float*)d_in[10];
  const float* gv = (const float*)d_in[11];
  const float* go = (const float*)d_in[12];
  const float* gnw = (const float*)d_in[13];
  const float* invf = (const float*)d_in[14];
  float* out = (float*)d_out;
  char* ws = (char*)d_ws;

  u16*   wq1    = (u16*)(ws);                   // 2304x768 fp16
  u16*   wo1    = (u16*)(ws + 3538944);         // 768x768
  u16*   wq2    = (u16*)(ws + 4718592);
  u16*   wo2    = (u16*)(ws + 8257536);
  float* tab    = (float*)(ws + 9437184);       // 512x32x2 f32
  u16*   normed = (u16*)(ws + 9568256);         // 8192x768 fp16
  u16*   obuf   = (u16*)(ws + 22151168);        // 8192x768 fp16
  float* h1     = (float*)(ws + 34734080);      // 8192x768 f32
  u16*   qkv    = (u16*)(ws + 59899904);        // 8192x2304 fp16

  const int WN = 768 * 768;
  WPtrs P;
  P.s[0] = tq;  P.d[0] = wq1;
  P.s[1] = tk;  P.d[1] = wq1 + WN;
  P.s[2] = tv;  P.d[2] = wq1 + 2 * WN;
  P.s[3] = to_; P.d[3] = wo1;
  P.s[4] = gq;  P.d[4] = wq2;
  P.s[5] = gk;  P.d[5] = wq2 + WN;
  P.s[6] = gv;  P.d[6] = wq2 + 2 * WN;
  P.s[7] = go;  P.d[7] = wo2;
  wconv8<<<4608, 256, 0, stream>>>(P);
  rope_tab_k<<<64, 256, 0, stream>>>(invf, tab);

  // pass 1 (time attention, causal + fused RoPE)
  rms_k<<<2048, 256, 0, stream>>>(hidden, tnw, normed);
  gemm_k<false, true, 0><<<dim3(64, 18), 256, 0, stream>>>(normed, wq1, QKVN, qkv, nullptr, nullptr, pids, tab);
  attn1_k<<<dim3(8, 192), 256, 0, stream>>>(qkv, obuf);
  gemm_k<true, false, 0><<<dim3(64, 6), 256, 0, stream>>>(obuf, wo1, DM, nullptr, h1, hidden, nullptr, nullptr);

  // pass 2 (group attention over batch dim; s-major token order)
  rms_k<<<2048, 256, 0, stream>>>(h1, gnw, normed);
  gemm_k<false, false, 1><<<dim3(64, 18), 256, 0, stream>>>(normed, wq2, QKVN, qkv, nullptr, nullptr, nullptr, nullptr);
  attn2_k<<<1536, 256, 0, stream>>>(qkv, gmask, obuf);
  gemm_k<true, false, 2><<<dim3(64, 6), 256, 0, stream>>>(obuf, wo2, DM, nullptr, out, h1, nullptr, nullptr);
}

// Round 5
// 235.802 us; speedup vs baseline: 1.1315x; 1.0603x over previous
//
#include <hip/hip_runtime.h>

#define DM   768
#define QKVN 2304
#define SQ   512
#define NB   16
#define NH   12

typedef unsigned short u16;
typedef _Float16 h16;
typedef _Float16 h16x8 __attribute__((ext_vector_type(8)));
typedef float f32x4 __attribute__((ext_vector_type(4)));

__device__ __forceinline__ u16 f2h(float f) {
  h16 h = (h16)f;
  return __builtin_bit_cast(u16, h);
}
__device__ __forceinline__ float h2f(u16 u) {
  return (float)__builtin_bit_cast(h16, u);
}
__device__ __forceinline__ void gload_lds16(const void* g, void* l) {
  __builtin_amdgcn_global_load_lds((__attribute__((address_space(1))) void*)(g),
                                   (__attribute__((address_space(3))) void*)(l), 16, 0, 0);
}

// ---------------- prep: 8x weight convert  U  rope table  U  pass-1 RMSNorm ----------------
struct WPtrs { const float* s[8]; u16* d[8]; };
__global__ __launch_bounds__(256) void prep_k(WPtrs P, const float* __restrict__ invf,
                                              float* __restrict__ tab,
                                              const float* __restrict__ x, const float* __restrict__ nw,
                                              u16* __restrict__ normed) {
  const int bid = blockIdx.x, tid = threadIdx.x;
  if (bid < 4608) {            // weight convert: 8 x 768x768
    int w = bid / 576;
    int i = ((bid % 576) * 256 + tid) * 4;
    float4 v = *reinterpret_cast<const float4*>(P.s[w] + i);
    ushort4 o;
    o.x = f2h(v.x); o.y = f2h(v.y); o.z = f2h(v.z); o.w = f2h(v.w);
    *reinterpret_cast<ushort4*>(P.d[w] + i) = o;
  } else if (bid < 4672) {     // rope table
    int i = (bid - 4608) * 256 + tid;   // 0..16383
    int pos = i >> 5, j = i & 31;
    float a = (float)pos * invf[j];
    float s, c;
    sincosf(a, &s, &c);
    tab[i * 2] = c; tab[i * 2 + 1] = s;
  } else {                     // RMSNorm pass 1: one wave per token
    int wv = tid >> 6, lane = tid & 63;
    size_t t = (size_t)(bid - 4672) * 4 + wv;
    const float* row = x + t * DM;
    float4 v[3];
    float ss = 0.f;
#pragma unroll
    for (int i = 0; i < 3; i++) {
      v[i] = *reinterpret_cast<const float4*>(row + (lane + 64 * i) * 4);
      ss += v[i].x * v[i].x + v[i].y * v[i].y + v[i].z * v[i].z + v[i].w * v[i].w;
    }
#pragma unroll
    for (int d = 1; d < 64; d <<= 1) ss += __shfl_xor(ss, d);
    float rs = rsqrtf(ss * (1.0f / 768.f) + 1e-6f);
    u16* orow = normed + t * DM;
#pragma unroll
    for (int i = 0; i < 3; i++) {
      int c = (lane + 64 * i) * 4;
      float4 wv4 = *reinterpret_cast<const float4*>(nw + c);
      ushort4 o;
      o.x = f2h(v[i].x * rs * wv4.x);
      o.y = f2h(v[i].y * rs * wv4.y);
      o.z = f2h(v[i].z * rs * wv4.z);
      o.w = f2h(v[i].w * rs * wv4.w);
      *reinterpret_cast<ushort4*>(orow + c) = o;
    }
  }
}

// ---------------- RMSNorm standalone (pass 2) ----------------
__global__ __launch_bounds__(256) void rms_k(const float* __restrict__ x, const float* __restrict__ w,
                                             u16* __restrict__ out) {
  int wv = threadIdx.x >> 6, lane = threadIdx.x & 63;
  size_t t = (size_t)blockIdx.x * 4 + wv;
  const float* row = x + t * DM;
  float4 v[3];
  float ss = 0.f;
#pragma unroll
  for (int i = 0; i < 3; i++) {
    v[i] = *reinterpret_cast<const float4*>(row + (lane + 64 * i) * 4);
    ss += v[i].x * v[i].x + v[i].y * v[i].y + v[i].z * v[i].z + v[i].w * v[i].w;
  }
#pragma unroll
  for (int d = 1; d < 64; d <<= 1) ss += __shfl_xor(ss, d);
  float rs = rsqrtf(ss * (1.0f / 768.f) + 1e-6f);
  u16* orow = out + t * DM;
#pragma unroll
  for (int i = 0; i < 3; i++) {
    int c = (lane + 64 * i) * 4;
    float4 wv4 = *reinterpret_cast<const float4*>(w + c);
    ushort4 o;
    o.x = f2h(v[i].x * rs * wv4.x);
    o.y = f2h(v[i].y * rs * wv4.y);
    o.z = f2h(v[i].z * rs * wv4.z);
    o.w = f2h(v[i].w * rs * wv4.w);
    *reinterpret_cast<ushort4*>(orow + c) = o;
  }
}

// ---------------- GEMM (unchanged from round 4) ----------------
template <bool RESID, bool ROPE, int PERM>
__global__ __launch_bounds__(256, 2) void gemm_k(const u16* __restrict__ A, const u16* __restrict__ W, int N,
                                              u16* __restrict__ Cb, float* __restrict__ Cf,
                                              const float* __restrict__ resid,
                                              const int* __restrict__ pids, const float* __restrict__ tab) {
  __shared__ __align__(16) char L[4 * 16384];   // 4 bufs x (A 8KB + B 8KB)
  const int tid = threadIdx.x, w = tid >> 6, lane = tid & 63;
  const int wr = w >> 1, wc = w & 1;
  int nf = blockIdx.y * gridDim.x + blockIdx.x;
  int nwg = gridDim.x * gridDim.y;
  int swv = (nf & 7) * (nwg >> 3) + (nf >> 3);
  const int bm = swv & 63;
  const int bnb = swv >> 6;
  const int l15 = lane & 15, l4 = lane >> 4;
  f32x4 acc[4][4] = {};

  const int r0 = tid >> 2, k40 = tid & 3;
  const int k4s = k40 ^ ((r0 >> 1) & 3);
  const size_t aA0 = (size_t)(bm * 128 + r0) * 1536 + k4s * 16;
  const size_t aA1 = (size_t)(bm * 128 + r0 + 64) * 1536 + k4s * 16;
  const size_t aB0 = (size_t)(bnb * 128 + r0) * 1536 + k4s * 16;
  const size_t aB1 = (size_t)(bnb * 128 + r0 + 64) * 1536 + k4s * 16;
  const int dc0 = tid * 16, dc1 = dc0 + 4096;
  const char* Ab = (const char*)A;
  const char* Wb = (const char*)W;

#define STAGE(T64, Q) do { \
    gload_lds16(Ab + aA0 + (T64), L + (Q) * 16384 + dc0); \
    gload_lds16(Ab + aA1 + (T64), L + (Q) * 16384 + dc1); \
    gload_lds16(Wb + aB0 + (T64), L + (Q) * 16384 + 8192 + dc0); \
    gload_lds16(Wb + aB1 + (T64), L + (Q) * 16384 + 8192 + dc1); \
  } while (0)

  int obA[4], obB[4];
#pragma unroll
  for (int i = 0; i < 4; i++) {
    int rowA = wr * 64 + i * 16 + l15;
    obA[i] = rowA * 64 + ((l4 ^ ((rowA >> 1) & 3)) * 16);
    int rowB = wc * 64 + i * 16 + l15;
    obB[i] = 8192 + rowB * 64 + ((l4 ^ ((rowB >> 1) & 3)) * 16);
  }

  STAGE(0, 0); STAGE(64, 1); STAGE(128, 2);
  asm volatile("s_waitcnt vmcnt(8)" ::: "memory");
  __builtin_amdgcn_sched_barrier(0);
  __builtin_amdgcn_s_barrier();
  __builtin_amdgcn_sched_barrier(0);

#pragma unroll
  for (int to = 0; to < 6; ++to) {
#pragma unroll
    for (int ti = 0; ti < 4; ++ti) {
      const int t = to * 4 + ti;
      const int tn = (t + 3 < 24) ? (t + 3) : 23;
      STAGE(tn * 64, (t + 3) & 3);
      const char* bq = L + (t & 3) * 16384;
      h16x8 am[4], bn[4];
#pragma unroll
      for (int i = 0; i < 4; i++) am[i] = *reinterpret_cast<const h16x8*>(bq + obA[i]);
#pragma unroll
      for (int j = 0; j < 4; j++) bn[j] = *reinterpret_cast<const h16x8*>(bq + obB[j]);
      __builtin_amdgcn_s_setprio(1);
#pragma unroll
      for (int i = 0; i < 4; i++)
#pragma unroll
        for (int j = 0; j < 4; j++)
          acc[i][j] = __builtin_amdgcn_mfma_f32_16x16x32_f16(am[i], bn[j], acc[i][j], 0, 0, 0);
      __builtin_amdgcn_s_setprio(0);
      asm volatile("s_waitcnt vmcnt(8)" ::: "memory");
      __builtin_amdgcn_sched_barrier(0);
      __builtin_amdgcn_s_barrier();
      __builtin_amdgcn_sched_barrier(0);
    }
  }
#undef STAGE
  asm volatile("s_waitcnt vmcnt(0)" ::: "memory");

  if (ROPE && bnb < 12) {
#pragma unroll
    for (int i = 0; i < 4; i++) {
      int row0 = bm * 128 + wr * 64 + i * 16 + l4 * 4;
#pragma unroll
      for (int r = 0; r < 4; r++) {
        int pos = pids[row0 + r];
        const float* tb = tab + pos * 64;
#pragma unroll
        for (int j = 0; j < 2; j++) {
          float2 cs = *reinterpret_cast<const float2*>(tb + 2 * (j * 16 + l15));
          float x1 = acc[i][j][r], x2 = acc[i][j + 2][r];
          acc[i][j][r]     = x1 * cs.x - x2 * cs.y;
          acc[i][j + 2][r] = x2 * cs.x + x1 * cs.y;
        }
      }
    }
  }
#pragma unroll
  for (int i = 0; i < 4; i++) {
    int row0 = bm * 128 + wr * 64 + i * 16 + l4 * 4;
#pragma unroll
    for (int j = 0; j < 4; j++) {
      int col = bnb * 128 + wc * 64 + j * 16 + l15;
#pragma unroll
      for (int r = 0; r < 4; r++) {
        int rr = row0 + r;
        int orow = (PERM == 0) ? rr : (PERM == 1) ? ((rr & 511) * 16 + (rr >> 9))
                                                  : ((rr & 15) * 512 + (rr >> 4));
        size_t idx = (size_t)orow * N + col;
        float v = acc[i][j][r];
        if (RESID) Cf[idx] = v + resid[idx];
        else Cb[idx] = f2h(v);
      }
    }
  }
}

// ---------------- V pre-transpose: vt[bh][d][s] = qkv[(b*512+s)][1536 + h*64 + d] ----------------
__global__ __launch_bounds__(256) void vtrans_k(const u16* __restrict__ qkv, u16* __restrict__ vt) {
  __shared__ u16 T[64][72];
  const int st = blockIdx.x, bh = blockIdx.y;
  const int b = bh / NH, h = bh % NH;
  const int t = threadIdx.x;
  {
    int s = t >> 2, d0 = (t & 3) * 16;
    const u16* src = qkv + ((size_t)(b * SQ + st * 64 + s)) * QKVN + 2 * DM + h * 64 + d0;
    ushort4 a0 = *reinterpret_cast<const ushort4*>(src + 0);
    ushort4 a1 = *reinterpret_cast<const ushort4*>(src + 4);
    ushort4 a2 = *reinterpret_cast<const ushort4*>(src + 8);
    ushort4 a3 = *reinterpret_cast<const ushort4*>(src + 12);
    *reinterpret_cast<ushort4*>(&T[s][d0 + 0])  = a0;
    *reinterpret_cast<ushort4*>(&T[s][d0 + 4])  = a1;
    *reinterpret_cast<ushort4*>(&T[s][d0 + 8])  = a2;
    *reinterpret_cast<ushort4*>(&T[s][d0 + 12]) = a3;
  }
  __syncthreads();
  {
    int d = t >> 2, k0 = (t & 3) * 16;
    u16* dst = vt + ((size_t)bh * 64 + d) * SQ + st * 64 + k0;
    ushort4 o[4];
#pragma unroll
    for (int i = 0; i < 16; i++) ((u16*)o)[i] = T[k0 + i][d];
#pragma unroll
    for (int i = 0; i < 4; i++) *reinterpret_cast<ushort4*>(dst + i * 4) = o[i];
  }
}

// ---------------- Pass-1 attention v2: KVBLK=128, dbuf prefetch, gload_lds K + V^T ----------------
__global__ __launch_bounds__(256) void attn1_k(const u16* __restrict__ qkv, const u16* __restrict__ vt,
                                               u16* __restrict__ O) {
  __shared__ __align__(16) char L[2][32768];   // [buf][ K 16KB | Vt 16KB ]
  __shared__ __align__(16) char Pl[4][4096];   // per-wave P [16 q][128 keys] swizzled
  const int qt = blockIdx.x;   // 0..7
  const int bh = blockIdx.y;   // 0..191
  const int b = bh / NH, h = bh % NH;
  const int tid = threadIdx.x, w = tid >> 6, lane = tid & 63;
  const int l15 = lane & 15, l4 = lane >> 4;
  // Q fragments (A-operand rows = l15)
  const size_t qoff = ((size_t)(b * SQ + qt * 64 + w * 16 + l15)) * QKVN + h * 64;
  h16x8 qf[2];
  qf[0] = *reinterpret_cast<const h16x8*>(qkv + qoff + 8 * l4);
  qf[1] = *reinterpret_cast<const h16x8*>(qkv + qoff + 32 + 8 * l4);
  f32x4 acco[4] = {};
  float mrun[4] = {-3e38f, -3e38f, -3e38f, -3e38f};
  float lrun[4] = {0.f, 0.f, 0.f, 0.f};
  const int qrow = qt * 64 + w * 16 + l4 * 4;  // + r
  const int nkt = (qt >> 1) + 1;

  // staging address pre-compute (halfs)
  const u16* Kg = qkv + (size_t)b * SQ * QKVN + DM + h * 64;   // + key*QKVN
  const int rK0 = tid >> 3;
  const size_t aK0 = (size_t)rK0 * QKVN + (size_t)(((tid & 7) ^ (rK0 & 7)) * 8);
  const u16* Vg = vt + (size_t)bh * 64 * SQ;                   // + d*SQ
  const int dV0 = tid >> 4;
  const size_t aV0 = (size_t)dV0 * SQ + (size_t)(((tid & 15) ^ (dV0 & 15)) * 8);
  const int dst0 = tid * 16;

#define STAGE1(KT, BUF) do { \
    _Pragma("unroll") \
    for (int e = 0; e < 4; e++) \
      gload_lds16(Kg + aK0 + (size_t)e * (32 * QKVN) + (size_t)(KT) * (128 * QKVN), \
                  L[BUF] + dst0 + e * 4096); \
    _Pragma("unroll") \
    for (int e = 0; e < 4; e++) \
      gload_lds16(Vg + aV0 + e * (16 * SQ) + (KT) * 128, \
                  L[BUF] + 16384 + dst0 + e * 4096); \
  } while (0)

  STAGE1(0, 0);
  asm volatile("s_waitcnt vmcnt(0)" ::: "memory");
  __builtin_amdgcn_sched_barrier(0);
  __builtin_amdgcn_s_barrier();
  __builtin_amdgcn_sched_barrier(0);

  for (int kt = 0; kt < nkt; ++kt) {
    const int cur = kt & 1;
    if (kt + 1 < nkt) STAGE1(kt + 1, cur ^ 1);
    const char* Kb = L[cur];
    const char* Vb = L[cur] + 16384;
    // scores = Q K^T : 128 keys (j 0..7), k' = d (kk 0..1)
    f32x4 sc[8] = {};
#pragma unroll
    for (int kk = 0; kk < 2; kk++) {
#pragma unroll
      for (int j = 0; j < 8; j++) {
        int row = j * 16 + l15;
        int off = row * 128 + (((kk * 4 + l4) ^ (row & 7)) * 16);
        h16x8 kf = *reinterpret_cast<const h16x8*>(Kb + off);
        sc[j] = __builtin_amdgcn_mfma_f32_16x16x32_f16(qf[kk], kf, sc[j], 0, 0, 0);
      }
    }
    float pv[8][4];
#pragma unroll
    for (int j = 0; j < 8; j++)
#pragma unroll
      for (int r = 0; r < 4; r++) pv[j][r] = sc[j][r];
    if (kt == nkt - 1) {  // tile containing the causal diagonal
#pragma unroll
      for (int r = 0; r < 4; r++) {
        int q = qrow + r;
#pragma unroll
        for (int j = 0; j < 8; j++) {
          int key = kt * 128 + j * 16 + l15;
          if (key > q) pv[j][r] = -1e30f;
        }
      }
    }
    float al[4];
#pragma unroll
    for (int r = 0; r < 4; r++) {
      float t0 = fmaxf(fmaxf(pv[0][r], pv[1][r]), fmaxf(pv[2][r], pv[3][r]));
      float t1 = fmaxf(fmaxf(pv[4][r], pv[5][r]), fmaxf(pv[6][r], pv[7][r]));
      float tm = fmaxf(t0, t1);
      tm = fmaxf(tm, __shfl_xor(tm, 1)); tm = fmaxf(tm, __shfl_xor(tm, 2));
      tm = fmaxf(tm, __shfl_xor(tm, 4)); tm = fmaxf(tm, __shfl_xor(tm, 8));
      float mn = fmaxf(mrun[r], tm);
      al[r] = __expf(mrun[r] - mn);
      mrun[r] = mn;
      float ts = 0.f;
#pragma unroll
      for (int j = 0; j < 8; j++) { float p = __expf(pv[j][r] - mn); pv[j][r] = p; ts += p; }
      ts += __shfl_xor(ts, 1); ts += __shfl_xor(ts, 2); ts += __shfl_xor(ts, 4); ts += __shfl_xor(ts, 8);
      lrun[r] = lrun[r] * al[r] + ts;
    }
#pragma unroll
    for (int j = 0; j < 4; j++)
#pragma unroll
      for (int r = 0; r < 4; r++) acco[j][r] *= al[r];
    // P -> per-wave LDS [q][128 keys], chunk swizzle c ^= (q & 15)
    char* pw = Pl[w];
#pragma unroll
    for (int r = 0; r < 4; r++) {
      int q = l4 * 4 + r;
#pragma unroll
      for (int j = 0; j < 8; j++) {
        int cw = j * 2 + (l15 >> 3);
        int byte = q * 256 + ((cw ^ (q & 15)) * 16) + (l15 & 7) * 2;
        *(u16*)(pw + byte) = f2h(pv[j][r]);
      }
    }
    asm volatile("s_waitcnt lgkmcnt(0)" ::: "memory");
    __builtin_amdgcn_sched_barrier(0);
    // out += P V : contract 128 keys (kk 0..3), d cols (j 0..3)
#pragma unroll
    for (int kk = 0; kk < 4; kk++) {
      h16x8 pa = *reinterpret_cast<const h16x8*>(pw + l15 * 256 + (((kk * 4 + l4) ^ l15) * 16));
#pragma unroll
      for (int j = 0; j < 4; j++) {
        int d = j * 16 + l15;
        int voff = d * 256 + (((kk * 4 + l4) ^ (d & 15)) * 16);
        h16x8 vf = *reinterpret_cast<const h16x8*>(Vb + voff);
        acco[j] = __builtin_amdgcn_mfma_f32_16x16x32_f16(pa, vf, acco[j], 0, 0, 0);
      }
    }
    asm volatile("s_waitcnt vmcnt(0)" ::: "memory");
    __builtin_amdgcn_sched_barrier(0);
    __builtin_amdgcn_s_barrier();
    __builtin_amdgcn_sched_barrier(0);
  }
#undef STAGE1
  // normalize + store (b-major rows)
#pragma unroll
  for (int r = 0; r < 4; r++) {
    float inv = 1.f / lrun[r];
    size_t orow = ((size_t)(b * SQ + qrow + r)) * DM + h * 64;
#pragma unroll
    for (int j = 0; j < 4; j++) O[orow + j * 16 + l15] = f2h(acco[j][r] * inv);
  }
}

// ---------------- Pass-2 attention: 16x16 per (s,h), one wave each (s-major qkv) ----------------
__global__ __launch_bounds__(256) void attn2_k(const u16* __restrict__ qkv, const float* __restrict__ gmask,
                                               u16* __restrict__ O) {
  __shared__ float Pl[4][16][16];
  __shared__ float Vl[4][16][68];
  const int tid = threadIdx.x, w = tid >> 6, lane = tid & 63;
  const int idx = blockIdx.x * 4 + w;
  const int s = idx / NH, h = idx % NH;
  const int l15 = lane & 15, l4 = lane >> 4;
  const size_t base = ((size_t)(s * 16 + l15)) * QKVN + h * 64;
  h16x8 qf0 = *reinterpret_cast<const h16x8*>(qkv + base + 8 * l4);
  h16x8 qf1 = *reinterpret_cast<const h16x8*>(qkv + base + 32 + 8 * l4);
  h16x8 kf0 = *reinterpret_cast<const h16x8*>(qkv + base + DM + 8 * l4);
  h16x8 kf1 = *reinterpret_cast<const h16x8*>(qkv + base + DM + 32 + 8 * l4);
  f32x4 sc = {};
  sc = __builtin_amdgcn_mfma_f32_16x16x32_f16(qf0, kf0, sc, 0, 0, 0);
  sc = __builtin_amdgcn_mfma_f32_16x16x32_f16(qf1, kf1, sc, 0, 0, 0);
  {
    int key = lane >> 2, d0 = (lane & 3) * 16;
    const u16* vsrc = qkv + ((size_t)(s * 16 + key)) * QKVN + 2 * DM + h * 64 + d0;
#pragma unroll
    for (int i = 0; i < 16; i += 4) {
      ushort4 vv = *reinterpret_cast<const ushort4*>(vsrc + i);
      Vl[w][key][d0 + i + 0] = h2f(vv.x);
      Vl[w][key][d0 + i + 1] = h2f(vv.y);
      Vl[w][key][d0 + i + 2] = h2f(vv.z);
      Vl[w][key][d0 + i + 3] = h2f(vv.w);
    }
  }
  const float* gm = gmask + ((size_t)s * NH + h) * 256;
#pragma unroll
  for (int r = 0; r < 4; r++) {
    float v = sc[r] + gm[(l4 * 4 + r) * 16 + l15];
    float mx = v;
    mx = fmaxf(mx, __shfl_xor(mx, 1)); mx = fmaxf(mx, __shfl_xor(mx, 2));
    mx = fmaxf(mx, __shfl_xor(mx, 4)); mx = fmaxf(mx, __shfl_xor(mx, 8));
    float p = __expf(v - mx);
    float su = p;
    su += __shfl_xor(su, 1); su += __shfl_xor(su, 2); su += __shfl_xor(su, 4); su += __shfl_xor(su, 8);
    Pl[w][l4 * 4 + r][l15] = p / su;
  }
  asm volatile("s_waitcnt lgkmcnt(0)" ::: "memory");
  __builtin_amdgcn_sched_barrier(0);
  const int q = lane >> 2, d0 = (lane & 3) * 16;
  float o[16] = {};
#pragma unroll
  for (int key = 0; key < 16; key++) {
    float pp = Pl[w][q][key];
#pragma unroll
    for (int dd = 0; dd < 16; dd += 4) {
      float4 vv = *reinterpret_cast<const float4*>(&Vl[w][key][d0 + dd]);
      o[dd + 0] += pp * vv.x; o[dd + 1] += pp * vv.y; o[dd + 2] += pp * vv.z; o[dd + 3] += pp * vv.w;
    }
  }
  u16* orow = O + ((size_t)(s * 16 + q)) * DM + h * 64 + d0;
#pragma unroll
  for (int i = 0; i < 16; i += 4) {
    ushort4 ov;
    ov.x = f2h(o[i]); ov.y = f2h(o[i + 1]); ov.z = f2h(o[i + 2]); ov.w = f2h(o[i + 3]);
    *reinterpret_cast<ushort4*>(orow + i) = ov;
  }
}

// ---------------- launch ----------------
extern "C" void kernel_launch(void* const* d_in, const int* in_sizes, int n_in,
                              void* d_out, int out_size, void* d_ws, size_t ws_size,
                              hipStream_t stream) {
  const float* hidden = (const float*)d_in[0];
  const int*   pids   = (const int*)d_in[1];
  const float* gmask  = (const float*)d_in[3];
  const float* tq = (const float*)d_in[4];
  const float* tk = (const float*)d_in[5];
  const float* tv = (const float*)d_in[6];
  const float* to_ = (const float*)d_in[7];
  const float* tnw = (const float*)d_in[8];
  const float* gq = (const float*)d_in[9];
  const float* gk = (const float*)d_in[10];
  const float* gv = (const float*)d_in[11];
  const float* go = (const float*)d_in[12];
  const float* gnw = (const float*)d_in[13];
  const float* invf = (const float*)d_in[14];
  float* out = (float*)d_out;
  char* ws = (char*)d_ws;

  u16*   wq1    = (u16*)(ws);                   // 2304x768 fp16
  u16*   wo1    = (u16*)(ws + 3538944);         // 768x768
  u16*   wq2    = (u16*)(ws + 4718592);
  u16*   wo2    = (u16*)(ws + 8257536);
  float* tab    = (float*)(ws + 9437184);       // 512x32x2 f32
  u16*   normed = (u16*)(ws + 9568256);         // 8192x768 fp16
  u16*   obuf   = (u16*)(ws + 22151168);        // 8192x768 fp16
  float* h1     = (float*)(ws + 34734080);      // 8192x768 f32
  u16*   qkv    = (u16*)(ws + 59899904);        // 8192x2304 fp16
  u16*   vt     = (u16*)(ws + 97648640);        // 192 x 64 x 512 fp16 (12.6 MB)

  const int WN = 768 * 768;
  WPtrs P;
  P.s[0] = tq;  P.d[0] = wq1;
  P.s[1] = tk;  P.d[1] = wq1 + WN;
  P.s[2] = tv;  P.d[2] = wq1 + 2 * WN;
  P.s[3] = to_; P.d[3] = wo1;
  P.s[4] = gq;  P.d[4] = wq2;
  P.s[5] = gk;  P.d[5] = wq2 + WN;
  P.s[6] = gv;  P.d[6] = wq2 + 2 * WN;
  P.s[7] = go;  P.d[7] = wo2;

  // pass 1 (time attention, causal + fused RoPE)
  prep_k<<<6720, 256, 0, stream>>>(P, invf, tab, hidden, tnw, normed);
  gemm_k<false, true, 0><<<dim3(64, 18), 256, 0, stream>>>(normed, wq1, QKVN, qkv, nullptr, nullptr, pids, tab);
  vtrans_k<<<dim3(8, 192), 256, 0, stream>>>(qkv, vt);
  attn1_k<<<dim3(8, 192), 256, 0, stream>>>(qkv, vt, obuf);
  gemm_k<true, false, 0><<<dim3(64, 6), 256, 0, stream>>>(obuf, wo1, DM, nullptr, h1, hidden, nullptr, nullptr);

  // pass 2 (group attention over batch dim; s-major token order)
  rms_k<<<2048, 256, 0, stream>>>(h1, gnw, normed);
  gemm_k<false, false, 1><<<dim3(64, 18), 256, 0, stream>>>(normed, wq2, QKVN, qkv, nullptr, nullptr, nullptr, nullptr);
  attn2_k<<<1536, 256, 0, stream>>>(qkv, gmask, obuf);
  gemm_k<true, false, 2><<<dim3(64, 6), 256, 0, stream>>>(obuf, wo2, DM, nullptr, out, h1, nullptr, nullptr);
}

// Round 6
// 216.927 us; speedup vs baseline: 1.2300x; 1.0870x over previous
//
#include <hip/hip_runtime.h>

#define DM   768
#define QKVN 2304
#define SQ   512
#define NB   16
#define NH   12

typedef unsigned short u16;
typedef _Float16 h16;
typedef _Float16 h16x8 __attribute__((ext_vector_type(8)));
typedef float f32x4 __attribute__((ext_vector_type(4)));

__device__ __forceinline__ u16 f2h(float f) {
  h16 h = (h16)f;
  return __builtin_bit_cast(u16, h);
}
__device__ __forceinline__ float h2f(u16 u) {
  return (float)__builtin_bit_cast(h16, u);
}
__device__ __forceinline__ void gload_lds16(const void* g, void* l) {
  __builtin_amdgcn_global_load_lds((__attribute__((address_space(1))) void*)(g),
                                   (__attribute__((address_space(3))) void*)(l), 16, 0, 0);
}

// ---------------- prep: 8x weight convert  U  rope table  U  pass-1 RMSNorm ----------------
struct WPtrs { const float* s[8]; u16* d[8]; };
__global__ __launch_bounds__(256) void prep_k(WPtrs P, const float* __restrict__ invf,
                                              float* __restrict__ tab,
                                              const float* __restrict__ x, const float* __restrict__ nw,
                                              u16* __restrict__ normed) {
  const int bid = blockIdx.x, tid = threadIdx.x;
  if (bid < 4608) {            // weight convert: 8 x 768x768
    int w = bid / 576;
    int i = ((bid % 576) * 256 + tid) * 4;
    float4 v = *reinterpret_cast<const float4*>(P.s[w] + i);
    ushort4 o;
    o.x = f2h(v.x); o.y = f2h(v.y); o.z = f2h(v.z); o.w = f2h(v.w);
    *reinterpret_cast<ushort4*>(P.d[w] + i) = o;
  } else if (bid < 4672) {     // rope table
    int i = (bid - 4608) * 256 + tid;   // 0..16383
    int pos = i >> 5, j = i & 31;
    float a = (float)pos * invf[j];
    float s, c;
    sincosf(a, &s, &c);
    tab[i * 2] = c; tab[i * 2 + 1] = s;
  } else {                     // RMSNorm pass 1: one wave per token
    int wv = tid >> 6, lane = tid & 63;
    size_t t = (size_t)(bid - 4672) * 4 + wv;
    const float* row = x + t * DM;
    float4 v[3];
    float ss = 0.f;
#pragma unroll
    for (int i = 0; i < 3; i++) {
      v[i] = *reinterpret_cast<const float4*>(row + (lane + 64 * i) * 4);
      ss += v[i].x * v[i].x + v[i].y * v[i].y + v[i].z * v[i].z + v[i].w * v[i].w;
    }
#pragma unroll
    for (int d = 1; d < 64; d <<= 1) ss += __shfl_xor(ss, d);
    float rs = rsqrtf(ss * (1.0f / 768.f) + 1e-6f);
    u16* orow = normed + t * DM;
#pragma unroll
    for (int i = 0; i < 3; i++) {
      int c = (lane + 64 * i) * 4;
      float4 wv4 = *reinterpret_cast<const float4*>(nw + c);
      ushort4 o;
      o.x = f2h(v[i].x * rs * wv4.x);
      o.y = f2h(v[i].y * rs * wv4.y);
      o.z = f2h(v[i].z * rs * wv4.z);
      o.w = f2h(v[i].w * rs * wv4.w);
      *reinterpret_cast<ushort4*>(orow + c) = o;
    }
  }
}

// ---------------- RMSNorm standalone (pass 2) ----------------
__global__ __launch_bounds__(256) void rms_k(const float* __restrict__ x, const float* __restrict__ w,
                                             u16* __restrict__ out) {
  int wv = threadIdx.x >> 6, lane = threadIdx.x & 63;
  size_t t = (size_t)blockIdx.x * 4 + wv;
  const float* row = x + t * DM;
  float4 v[3];
  float ss = 0.f;
#pragma unroll
  for (int i = 0; i < 3; i++) {
    v[i] = *reinterpret_cast<const float4*>(row + (lane + 64 * i) * 4);
    ss += v[i].x * v[i].x + v[i].y * v[i].y + v[i].z * v[i].z + v[i].w * v[i].w;
  }
#pragma unroll
  for (int d = 1; d < 64; d <<= 1) ss += __shfl_xor(ss, d);
  float rs = rsqrtf(ss * (1.0f / 768.f) + 1e-6f);
  u16* orow = out + t * DM;
#pragma unroll
  for (int i = 0; i < 3; i++) {
    int c = (lane + 64 * i) * 4;
    float4 wv4 = *reinterpret_cast<const float4*>(w + c);
    ushort4 o;
    o.x = f2h(v[i].x * rs * wv4.x);
    o.y = f2h(v[i].y * rs * wv4.y);
    o.z = f2h(v[i].z * rs * wv4.z);
    o.w = f2h(v[i].w * rs * wv4.w);
    *reinterpret_cast<ushort4*>(orow + c) = o;
  }
}

// ---------------- GEMM: C[M=8192,N] = A[M,768] * W[N,768]^T (both fp16, K-major) ----------------
// 128x128 tile, BK=32, 4-deep counted-vmcnt pipeline, setprio, XCD chunking.
// Round-6 change: bnb-MINOR decode inside each XCD chunk -> concurrent blocks per XCD span
// ~3.5 bm x all bnb => A (0.7MB) + B (3.5MB) fit the 4MB per-XCD L2 (was: all 64 bm, A 12.6MB, thrash).
template <bool RESID, bool ROPE, int PERM>
__global__ __launch_bounds__(256, 2) void gemm_k(const u16* __restrict__ A, const u16* __restrict__ W, int N,
                                              u16* __restrict__ Cb, float* __restrict__ Cf,
                                              const float* __restrict__ resid,
                                              const int* __restrict__ pids, const float* __restrict__ tab) {
  __shared__ __align__(16) char L[4 * 16384];   // 4 bufs x (A 8KB + B 8KB)
  const int tid = threadIdx.x, w = tid >> 6, lane = tid & 63;
  const int wr = w >> 1, wc = w & 1;
  const int nbn = gridDim.y;                    // N/128
  int nf = blockIdx.y * gridDim.x + blockIdx.x;
  int nwg = gridDim.x * nbn;
  int swv = (nf & 7) * (nwg >> 3) + (nf >> 3);  // XCD-contiguous chunks (nwg%8==0)
  const int bm = swv / nbn;                     // bnb-minor within chunk
  const int bnb = swv % nbn;
  const int l15 = lane & 15, l4 = lane >> 4;
  f32x4 acc[4][4] = {};

  const int r0 = tid >> 2, k40 = tid & 3;
  const int k4s = k40 ^ ((r0 >> 1) & 3);
  const size_t aA0 = (size_t)(bm * 128 + r0) * 1536 + k4s * 16;
  const size_t aA1 = (size_t)(bm * 128 + r0 + 64) * 1536 + k4s * 16;
  const size_t aB0 = (size_t)(bnb * 128 + r0) * 1536 + k4s * 16;
  const size_t aB1 = (size_t)(bnb * 128 + r0 + 64) * 1536 + k4s * 16;
  const int dc0 = tid * 16, dc1 = dc0 + 4096;
  const char* Ab = (const char*)A;
  const char* Wb = (const char*)W;

#define STAGE(T64, Q) do { \
    gload_lds16(Ab + aA0 + (T64), L + (Q) * 16384 + dc0); \
    gload_lds16(Ab + aA1 + (T64), L + (Q) * 16384 + dc1); \
    gload_lds16(Wb + aB0 + (T64), L + (Q) * 16384 + 8192 + dc0); \
    gload_lds16(Wb + aB1 + (T64), L + (Q) * 16384 + 8192 + dc1); \
  } while (0)

  int obA[4], obB[4];
#pragma unroll
  for (int i = 0; i < 4; i++) {
    int rowA = wr * 64 + i * 16 + l15;
    obA[i] = rowA * 64 + ((l4 ^ ((rowA >> 1) & 3)) * 16);
    int rowB = wc * 64 + i * 16 + l15;
    obB[i] = 8192 + rowB * 64 + ((l4 ^ ((rowB >> 1) & 3)) * 16);
  }

  STAGE(0, 0); STAGE(64, 1); STAGE(128, 2);
  asm volatile("s_waitcnt vmcnt(8)" ::: "memory");
  __builtin_amdgcn_sched_barrier(0);
  __builtin_amdgcn_s_barrier();
  __builtin_amdgcn_sched_barrier(0);

#pragma unroll
  for (int to = 0; to < 6; ++to) {
#pragma unroll
    for (int ti = 0; ti < 4; ++ti) {
      const int t = to * 4 + ti;
      const int tn = (t + 3 < 24) ? (t + 3) : 23;
      STAGE(tn * 64, (t + 3) & 3);
      const char* bq = L + (t & 3) * 16384;
      h16x8 am[4], bn[4];
#pragma unroll
      for (int i = 0; i < 4; i++) am[i] = *reinterpret_cast<const h16x8*>(bq + obA[i]);
#pragma unroll
      for (int j = 0; j < 4; j++) bn[j] = *reinterpret_cast<const h16x8*>(bq + obB[j]);
      __builtin_amdgcn_s_setprio(1);
#pragma unroll
      for (int i = 0; i < 4; i++)
#pragma unroll
        for (int j = 0; j < 4; j++)
          acc[i][j] = __builtin_amdgcn_mfma_f32_16x16x32_f16(am[i], bn[j], acc[i][j], 0, 0, 0);
      __builtin_amdgcn_s_setprio(0);
      asm volatile("s_waitcnt vmcnt(8)" ::: "memory");
      __builtin_amdgcn_sched_barrier(0);
      __builtin_amdgcn_s_barrier();
      __builtin_amdgcn_sched_barrier(0);
    }
  }
#undef STAGE
  asm volatile("s_waitcnt vmcnt(0)" ::: "memory");

  if (ROPE && bnb < 12) {
#pragma unroll
    for (int i = 0; i < 4; i++) {
      int row0 = bm * 128 + wr * 64 + i * 16 + l4 * 4;
#pragma unroll
      for (int r = 0; r < 4; r++) {
        int pos = pids[row0 + r];
        const float* tb = tab + pos * 64;
#pragma unroll
        for (int j = 0; j < 2; j++) {
          float2 cs = *reinterpret_cast<const float2*>(tb + 2 * (j * 16 + l15));
          float x1 = acc[i][j][r], x2 = acc[i][j + 2][r];
          acc[i][j][r]     = x1 * cs.x - x2 * cs.y;
          acc[i][j + 2][r] = x2 * cs.x + x1 * cs.y;
        }
      }
    }
  }
#pragma unroll
  for (int i = 0; i < 4; i++) {
    int row0 = bm * 128 + wr * 64 + i * 16 + l4 * 4;
#pragma unroll
    for (int j = 0; j < 4; j++) {
      int col = bnb * 128 + wc * 64 + j * 16 + l15;
#pragma unroll
      for (int r = 0; r < 4; r++) {
        int rr = row0 + r;
        int orow = (PERM == 0) ? rr : (PERM == 1) ? ((rr & 511) * 16 + (rr >> 9))
                                                  : ((rr & 15) * 512 + (rr >> 4));
        size_t idx = (size_t)orow * N + col;
        float v = acc[i][j][r];
        if (RESID) Cf[idx] = v + resid[idx];
        else Cb[idx] = f2h(v);
      }
    }
  }
}

// ---------------- V pre-transpose: vt[bh][d][s] = qkv[(b*512+s)][1536 + h*64 + d] ----------------
__global__ __launch_bounds__(256) void vtrans_k(const u16* __restrict__ qkv, u16* __restrict__ vt) {
  __shared__ u16 T[64][72];
  const int st = blockIdx.x, bh = blockIdx.y;
  const int b = bh / NH, h = bh % NH;
  const int t = threadIdx.x;
  {
    int s = t >> 2, d0 = (t & 3) * 16;
    const u16* src = qkv + ((size_t)(b * SQ + st * 64 + s)) * QKVN + 2 * DM + h * 64 + d0;
    ushort4 a0 = *reinterpret_cast<const ushort4*>(src + 0);
    ushort4 a1 = *reinterpret_cast<const ushort4*>(src + 4);
    ushort4 a2 = *reinterpret_cast<const ushort4*>(src + 8);
    ushort4 a3 = *reinterpret_cast<const ushort4*>(src + 12);
    *reinterpret_cast<ushort4*>(&T[s][d0 + 0])  = a0;
    *reinterpret_cast<ushort4*>(&T[s][d0 + 4])  = a1;
    *reinterpret_cast<ushort4*>(&T[s][d0 + 8])  = a2;
    *reinterpret_cast<ushort4*>(&T[s][d0 + 12]) = a3;
  }
  __syncthreads();
  {
    int d = t >> 2, k0 = (t & 3) * 16;
    u16* dst = vt + ((size_t)bh * 64 + d) * SQ + st * 64 + k0;
    ushort4 o[4];
#pragma unroll
    for (int i = 0; i < 16; i++) ((u16*)o)[i] = T[k0 + i][d];
#pragma unroll
    for (int i = 0; i < 4; i++) *reinterpret_cast<ushort4*>(dst + i * 4) = o[i];
  }
}

// ---------------- Pass-1 attention v2: KVBLK=128, dbuf prefetch, gload_lds K + V^T ----------------
__global__ __launch_bounds__(256) void attn1_k(const u16* __restrict__ qkv, const u16* __restrict__ vt,
                                               u16* __restrict__ O) {
  __shared__ __align__(16) char L[2][32768];   // [buf][ K 16KB | Vt 16KB ]
  __shared__ __align__(16) char Pl[4][4096];   // per-wave P [16 q][128 keys] swizzled
  const int qt = blockIdx.x;   // 0..7
  const int bh = blockIdx.y;   // 0..191
  const int b = bh / NH, h = bh % NH;
  const int tid = threadIdx.x, w = tid >> 6, lane = tid & 63;
  const int l15 = lane & 15, l4 = lane >> 4;
  const size_t qoff = ((size_t)(b * SQ + qt * 64 + w * 16 + l15)) * QKVN + h * 64;
  h16x8 qf[2];
  qf[0] = *reinterpret_cast<const h16x8*>(qkv + qoff + 8 * l4);
  qf[1] = *reinterpret_cast<const h16x8*>(qkv + qoff + 32 + 8 * l4);
  f32x4 acco[4] = {};
  float mrun[4] = {-3e38f, -3e38f, -3e38f, -3e38f};
  float lrun[4] = {0.f, 0.f, 0.f, 0.f};
  const int qrow = qt * 64 + w * 16 + l4 * 4;  // + r
  const int nkt = (qt >> 1) + 1;

  const u16* Kg = qkv + (size_t)b * SQ * QKVN + DM + h * 64;   // + key*QKVN
  const int rK0 = tid >> 3;
  const size_t aK0 = (size_t)rK0 * QKVN + (size_t)(((tid & 7) ^ (rK0 & 7)) * 8);
  const u16* Vg = vt + (size_t)bh * 64 * SQ;                   // + d*SQ
  const int dV0 = tid >> 4;
  const size_t aV0 = (size_t)dV0 * SQ + (size_t)(((tid & 15) ^ (dV0 & 15)) * 8);
  const int dst0 = tid * 16;

#define STAGE1(KT, BUF) do { \
    _Pragma("unroll") \
    for (int e = 0; e < 4; e++) \
      gload_lds16(Kg + aK0 + (size_t)e * (32 * QKVN) + (size_t)(KT) * (128 * QKVN), \
                  L[BUF] + dst0 + e * 4096); \
    _Pragma("unroll") \
    for (int e = 0; e < 4; e++) \
      gload_lds16(Vg + aV0 + e * (16 * SQ) + (KT) * 128, \
                  L[BUF] + 16384 + dst0 + e * 4096); \
  } while (0)

  STAGE1(0, 0);
  asm volatile("s_waitcnt vmcnt(0)" ::: "memory");
  __builtin_amdgcn_sched_barrier(0);
  __builtin_amdgcn_s_barrier();
  __builtin_amdgcn_sched_barrier(0);

  for (int kt = 0; kt < nkt; ++kt) {
    const int cur = kt & 1;
    if (kt + 1 < nkt) STAGE1(kt + 1, cur ^ 1);
    const char* Kb = L[cur];
    const char* Vb = L[cur] + 16384;
    f32x4 sc[8] = {};
    __builtin_amdgcn_s_setprio(1);
#pragma unroll
    for (int kk = 0; kk < 2; kk++) {
#pragma unroll
      for (int j = 0; j < 8; j++) {
        int row = j * 16 + l15;
        int off = row * 128 + (((kk * 4 + l4) ^ (row & 7)) * 16);
        h16x8 kf = *reinterpret_cast<const h16x8*>(Kb + off);
        sc[j] = __builtin_amdgcn_mfma_f32_16x16x32_f16(qf[kk], kf, sc[j], 0, 0, 0);
      }
    }
    __builtin_amdgcn_s_setprio(0);
    float pv[8][4];
#pragma unroll
    for (int j = 0; j < 8; j++)
#pragma unroll
      for (int r = 0; r < 4; r++) pv[j][r] = sc[j][r];
    if (kt == nkt - 1) {  // tile containing the causal diagonal
#pragma unroll
      for (int r = 0; r < 4; r++) {
        int q = qrow + r;
#pragma unroll
        for (int j = 0; j < 8; j++) {
          int key = kt * 128 + j * 16 + l15;
          if (key > q) pv[j][r] = -1e30f;
        }
      }
    }
    float al[4];
#pragma unroll
    for (int r = 0; r < 4; r++) {
      float t0 = fmaxf(fmaxf(pv[0][r], pv[1][r]), fmaxf(pv[2][r], pv[3][r]));
      float t1 = fmaxf(fmaxf(pv[4][r], pv[5][r]), fmaxf(pv[6][r], pv[7][r]));
      float tm = fmaxf(t0, t1);
      tm = fmaxf(tm, __shfl_xor(tm, 1)); tm = fmaxf(tm, __shfl_xor(tm, 2));
      tm = fmaxf(tm, __shfl_xor(tm, 4)); tm = fmaxf(tm, __shfl_xor(tm, 8));
      float mn = fmaxf(mrun[r], tm);
      al[r] = __expf(mrun[r] - mn);
      mrun[r] = mn;
      float ts = 0.f;
#pragma unroll
      for (int j = 0; j < 8; j++) { float p = __expf(pv[j][r] - mn); pv[j][r] = p; ts += p; }
      ts += __shfl_xor(ts, 1); ts += __shfl_xor(ts, 2); ts += __shfl_xor(ts, 4); ts += __shfl_xor(ts, 8);
      lrun[r] = lrun[r] * al[r] + ts;
    }
#pragma unroll
    for (int j = 0; j < 4; j++)
#pragma unroll
      for (int r = 0; r < 4; r++) acco[j][r] *= al[r];
    char* pw = Pl[w];
#pragma unroll
    for (int r = 0; r < 4; r++) {
      int q = l4 * 4 + r;
#pragma unroll
      for (int j = 0; j < 8; j++) {
        int cw = j * 2 + (l15 >> 3);
        int byte = q * 256 + ((cw ^ (q & 15)) * 16) + (l15 & 7) * 2;
        *(u16*)(pw + byte) = f2h(pv[j][r]);
      }
    }
    asm volatile("s_waitcnt lgkmcnt(0)" ::: "memory");
    __builtin_amdgcn_sched_barrier(0);
    __builtin_amdgcn_s_setprio(1);
#pragma unroll
    for (int kk = 0; kk < 4; kk++) {
      h16x8 pa = *reinterpret_cast<const h16x8*>(pw + l15 * 256 + (((kk * 4 + l4) ^ l15) * 16));
#pragma unroll
      for (int j = 0; j < 4; j++) {
        int d = j * 16 + l15;
        int voff = d * 256 + (((kk * 4 + l4) ^ (d & 15)) * 16);
        h16x8 vf = *reinterpret_cast<const h16x8*>(Vb + voff);
        acco[j] = __builtin_amdgcn_mfma_f32_16x16x32_f16(pa, vf, acco[j], 0, 0, 0);
      }
    }
    __builtin_amdgcn_s_setprio(0);
    asm volatile("s_waitcnt vmcnt(0)" ::: "memory");
    __builtin_amdgcn_sched_barrier(0);
    __builtin_amdgcn_s_barrier();
    __builtin_amdgcn_sched_barrier(0);
  }
#undef STAGE1
#pragma unroll
  for (int r = 0; r < 4; r++) {
    float inv = 1.f / lrun[r];
    size_t orow = ((size_t)(b * SQ + qrow + r)) * DM + h * 64;
#pragma unroll
    for (int j = 0; j < 4; j++) O[orow + j * 16 + l15] = f2h(acco[j][r] * inv);
  }
}

// ---------------- Pass-2 attention: 16x16 per (s,h), one wave each (s-major qkv) ----------------
__global__ __launch_bounds__(256) void attn2_k(const u16* __restrict__ qkv, const float* __restrict__ gmask,
                                               u16* __restrict__ O) {
  __shared__ float Pl[4][16][16];
  __shared__ float Vl[4][16][68];
  const int tid = threadIdx.x, w = tid >> 6, lane = tid & 63;
  const int idx = blockIdx.x * 4 + w;
  const int s = idx / NH, h = idx % NH;
  const int l15 = lane & 15, l4 = lane >> 4;
  const size_t base = ((size_t)(s * 16 + l15)) * QKVN + h * 64;
  h16x8 qf0 = *reinterpret_cast<const h16x8*>(qkv + base + 8 * l4);
  h16x8 qf1 = *reinterpret_cast<const h16x8*>(qkv + base + 32 + 8 * l4);
  h16x8 kf0 = *reinterpret_cast<const h16x8*>(qkv + base + DM + 8 * l4);
  h16x8 kf1 = *reinterpret_cast<const h16x8*>(qkv + base + DM + 32 + 8 * l4);
  f32x4 sc = {};
  sc = __builtin_amdgcn_mfma_f32_16x16x32_f16(qf0, kf0, sc, 0, 0, 0);
  sc = __builtin_amdgcn_mfma_f32_16x16x32_f16(qf1, kf1, sc, 0, 0, 0);
  {
    int key = lane >> 2, d0 = (lane & 3) * 16;
    const u16* vsrc = qkv + ((size_t)(s * 16 + key)) * QKVN + 2 * DM + h * 64 + d0;
#pragma unroll
    for (int i = 0; i < 16; i += 4) {
      ushort4 vv = *reinterpret_cast<const ushort4*>(vsrc + i);
      Vl[w][key][d0 + i + 0] = h2f(vv.x);
      Vl[w][key][d0 + i + 1] = h2f(vv.y);
      Vl[w][key][d0 + i + 2] = h2f(vv.z);
      Vl[w][key][d0 + i + 3] = h2f(vv.w);
    }
  }
  const float* gm = gmask + ((size_t)s * NH + h) * 256;
#pragma unroll
  for (int r = 0; r < 4; r++) {
    float v = sc[r] + gm[(l4 * 4 + r) * 16 + l15];
    float mx = v;
    mx = fmaxf(mx, __shfl_xor(mx, 1)); mx = fmaxf(mx, __shfl_xor(mx, 2));
    mx = fmaxf(mx, __shfl_xor(mx, 4)); mx = fmaxf(mx, __shfl_xor(mx, 8));
    float p = __expf(v - mx);
    float su = p;
    su += __shfl_xor(su, 1); su += __shfl_xor(su, 2); su += __shfl_xor(su, 4); su += __shfl_xor(su, 8);
    Pl[w][l4 * 4 + r][l15] = p / su;
  }
  asm volatile("s_waitcnt lgkmcnt(0)" ::: "memory");
  __builtin_amdgcn_sched_barrier(0);
  const int q = lane >> 2, d0 = (lane & 3) * 16;
  float o[16] = {};
#pragma unroll
  for (int key = 0; key < 16; key++) {
    float pp = Pl[w][q][key];
#pragma unroll
    for (int dd = 0; dd < 16; dd += 4) {
      float4 vv = *reinterpret_cast<const float4*>(&Vl[w][key][d0 + dd]);
      o[dd + 0] += pp * vv.x; o[dd + 1] += pp * vv.y; o[dd + 2] += pp * vv.z; o[dd + 3] += pp * vv.w;
    }
  }
  u16* orow = O + ((size_t)(s * 16 + q)) * DM + h * 64 + d0;
#pragma unroll
  for (int i = 0; i < 16; i += 4) {
    ushort4 ov;
    ov.x = f2h(o[i]); ov.y = f2h(o[i + 1]); ov.z = f2h(o[i + 2]); ov.w = f2h(o[i + 3]);
    *reinterpret_cast<ushort4*>(orow + i) = ov;
  }
}

// ---------------- launch ----------------
extern "C" void kernel_launch(void* const* d_in, const int* in_sizes, int n_in,
                              void* d_out, int out_size, void* d_ws, size_t ws_size,
                              hipStream_t stream) {
  const float* hidden = (const float*)d_in[0];
  const int*   pids   = (const int*)d_in[1];
  const float* gmask  = (const float*)d_in[3];
  const float* tq = (const float*)d_in[4];
  const float* tk = (const float*)d_in[5];
  const float* tv = (const float*)d_in[6];
  const float* to_ = (const float*)d_in[7];
  const float* tnw = (const float*)d_in[8];
  const float* gq = (const float*)d_in[9];
  const float* gk = (const float*)d_in[10];
  const float* gv = (const float*)d_in[11];
  const float* go = (const float*)d_in[12];
  const float* gnw = (const float*)d_in[13];
  const float* invf = (const float*)d_in[14];
  float* out = (float*)d_out;
  char* ws = (char*)d_ws;

  u16*   wq1    = (u16*)(ws);                   // 2304x768 fp16
  u16*   wo1    = (u16*)(ws + 3538944);         // 768x768
  u16*   wq2    = (u16*)(ws + 4718592);
  u16*   wo2    = (u16*)(ws + 8257536);
  float* tab    = (float*)(ws + 9437184);       // 512x32x2 f32
  u16*   normed = (u16*)(ws + 9568256);         // 8192x768 fp16
  u16*   obuf   = (u16*)(ws + 22151168);        // 8192x768 fp16
  float* h1     = (float*)(ws + 34734080);      // 8192x768 f32
  u16*   qkv    = (u16*)(ws + 59899904);        // 8192x2304 fp16
  u16*   vt     = (u16*)(ws + 97648640);        // 192 x 64 x 512 fp16 (12.6 MB)

  const int WN = 768 * 768;
  WPtrs P;
  P.s[0] = tq;  P.d[0] = wq1;
  P.s[1] = tk;  P.d[1] = wq1 + WN;
  P.s[2] = tv;  P.d[2] = wq1 + 2 * WN;
  P.s[3] = to_; P.d[3] = wo1;
  P.s[4] = gq;  P.d[4] = wq2;
  P.s[5] = gk;  P.d[5] = wq2 + WN;
  P.s[6] = gv;  P.d[6] = wq2 + 2 * WN;
  P.s[7] = go;  P.d[7] = wo2;

  // pass 1 (time attention, causal + fused RoPE)
  prep_k<<<6720, 256, 0, stream>>>(P, invf, tab, hidden, tnw, normed);
  gemm_k<false, true, 0><<<dim3(64, 18), 256, 0, stream>>>(normed, wq1, QKVN, qkv, nullptr, nullptr, pids, tab);
  vtrans_k<<<dim3(8, 192), 256, 0, stream>>>(qkv, vt);
  attn1_k<<<dim3(8, 192), 256, 0, stream>>>(qkv, vt, obuf);
  gemm_k<true, false, 0><<<dim3(64, 6), 256, 0, stream>>>(obuf, wo1, DM, nullptr, h1, hidden, nullptr, nullptr);

  // pass 2 (group attention over batch dim; s-major token order)
  rms_k<<<2048, 256, 0, stream>>>(h1, gnw, normed);
  gemm_k<false, false, 1><<<dim3(64, 18), 256, 0, stream>>>(normed, wq2, QKVN, qkv, nullptr, nullptr, nullptr, nullptr);
  attn2_k<<<1536, 256, 0, stream>>>(qkv, gmask, obuf);
  gemm_k<true, false, 2><<<dim3(64, 6), 256, 0, stream>>>(obuf, wo2, DM, nullptr, out, h1, nullptr, nullptr);
}

// Round 7
// 208.697 us; speedup vs baseline: 1.2785x; 1.0394x over previous
//
#include <hip/hip_runtime.h>

#define DM   768
#define QKVN 2304
#define SQ   512
#define NB   16
#define NH   12

typedef unsigned short u16;
typedef _Float16 h16;
typedef _Float16 h16x8 __attribute__((ext_vector_type(8)));
typedef float f32x4 __attribute__((ext_vector_type(4)));

__device__ __forceinline__ u16 f2h(float f) {
  h16 h = (h16)f;
  return __builtin_bit_cast(u16, h);
}
__device__ __forceinline__ float h2f(u16 u) {
  return (float)__builtin_bit_cast(h16, u);
}
__device__ __forceinline__ void gload_lds16(const void* g, void* l) {
  __builtin_amdgcn_global_load_lds((__attribute__((address_space(1))) void*)(g),
                                   (__attribute__((address_space(3))) void*)(l), 16, 0, 0);
}

// ---------------- prep: 8x weight convert  U  rope table  U  pass-1 RMSNorm ----------------
struct WPtrs { const float* s[8]; u16* d[8]; };
__global__ __launch_bounds__(256) void prep_k(WPtrs P, const float* __restrict__ invf,
                                              float* __restrict__ tab,
                                              const float* __restrict__ x, const float* __restrict__ nw,
                                              u16* __restrict__ normed) {
  const int bid = blockIdx.x, tid = threadIdx.x;
  if (bid < 4608) {            // weight convert: 8 x 768x768
    int w = bid / 576;
    int i = ((bid % 576) * 256 + tid) * 4;
    float4 v = *reinterpret_cast<const float4*>(P.s[w] + i);
    ushort4 o;
    o.x = f2h(v.x); o.y = f2h(v.y); o.z = f2h(v.z); o.w = f2h(v.w);
    *reinterpret_cast<ushort4*>(P.d[w] + i) = o;
  } else if (bid < 4672) {     // rope table
    int i = (bid - 4608) * 256 + tid;   // 0..16383
    int pos = i >> 5, j = i & 31;
    float a = (float)pos * invf[j];
    float s, c;
    sincosf(a, &s, &c);
    tab[i * 2] = c; tab[i * 2 + 1] = s;
  } else {                     // RMSNorm pass 1: one wave per token
    int wv = tid >> 6, lane = tid & 63;
    size_t t = (size_t)(bid - 4672) * 4 + wv;
    const float* row = x + t * DM;
    float4 v[3];
    float ss = 0.f;
#pragma unroll
    for (int i = 0; i < 3; i++) {
      v[i] = *reinterpret_cast<const float4*>(row + (lane + 64 * i) * 4);
      ss += v[i].x * v[i].x + v[i].y * v[i].y + v[i].z * v[i].z + v[i].w * v[i].w;
    }
#pragma unroll
    for (int d = 1; d < 64; d <<= 1) ss += __shfl_xor(ss, d);
    float rs = rsqrtf(ss * (1.0f / 768.f) + 1e-6f);
    u16* orow = normed + t * DM;
#pragma unroll
    for (int i = 0; i < 3; i++) {
      int c = (lane + 64 * i) * 4;
      float4 wv4 = *reinterpret_cast<const float4*>(nw + c);
      ushort4 o;
      o.x = f2h(v[i].x * rs * wv4.x);
      o.y = f2h(v[i].y * rs * wv4.y);
      o.z = f2h(v[i].z * rs * wv4.z);
      o.w = f2h(v[i].w * rs * wv4.w);
      *reinterpret_cast<ushort4*>(orow + c) = o;
    }
  }
}

// ---------------- RMSNorm pass 2: fp16 input (h1) ----------------
__global__ __launch_bounds__(256) void rms_k(const u16* __restrict__ x, const float* __restrict__ w,
                                             u16* __restrict__ out) {
  int wv = threadIdx.x >> 6, lane = threadIdx.x & 63;
  size_t t = (size_t)blockIdx.x * 4 + wv;
  const u16* row = x + t * DM;
  float4 v[3];
  float ss = 0.f;
#pragma unroll
  for (int i = 0; i < 3; i++) {
    ushort4 rw = *reinterpret_cast<const ushort4*>(row + (lane + 64 * i) * 4);
    v[i].x = h2f(rw.x); v[i].y = h2f(rw.y); v[i].z = h2f(rw.z); v[i].w = h2f(rw.w);
    ss += v[i].x * v[i].x + v[i].y * v[i].y + v[i].z * v[i].z + v[i].w * v[i].w;
  }
#pragma unroll
  for (int d = 1; d < 64; d <<= 1) ss += __shfl_xor(ss, d);
  float rs = rsqrtf(ss * (1.0f / 768.f) + 1e-6f);
  u16* orow = out + t * DM;
#pragma unroll
  for (int i = 0; i < 3; i++) {
    int c = (lane + 64 * i) * 4;
    float4 wv4 = *reinterpret_cast<const float4*>(w + c);
    ushort4 o;
    o.x = f2h(v[i].x * rs * wv4.x);
    o.y = f2h(v[i].y * rs * wv4.y);
    o.z = f2h(v[i].z * rs * wv4.z);
    o.w = f2h(v[i].w * rs * wv4.w);
    *reinterpret_cast<ushort4*>(orow + c) = o;
  }
}

// ---------------- GEMM: C[M=8192,N] = A[M,768] * W[N,768]^T (both fp16, K-major) ----------------
// 128x128 tile, BK=32, 4-deep counted-vmcnt pipeline, setprio, XCD chunking (bnb-minor, L2-resident).
// CMODE: 0 = fp16 C; 1 = fp16 C = acc + f32 resid (h1 spine); 2 = f32 C = acc + fp16 resid.
// VT (QKV pass 1 only): blocks bnb>=12 (V columns) write TRANSPOSED into vt[bh][d][s]; qkv V region unused.
template <int CMODE, bool ROPE, int PERM, bool VT>
__global__ __launch_bounds__(256, 2) void gemm_k(const u16* __restrict__ A, const u16* __restrict__ W, int N,
                                              void* __restrict__ C, const void* __restrict__ resid,
                                              const int* __restrict__ pids, const float* __restrict__ tab,
                                              u16* __restrict__ vt) {
  __shared__ __align__(16) char L[4 * 16384];   // 4 bufs x (A 8KB + B 8KB)
  const int tid = threadIdx.x, w = tid >> 6, lane = tid & 63;
  const int wr = w >> 1, wc = w & 1;
  const int nbn = gridDim.y;                    // N/128
  int nf = blockIdx.y * gridDim.x + blockIdx.x;
  int nwg = gridDim.x * nbn;
  int swv = (nf & 7) * (nwg >> 3) + (nf >> 3);  // XCD-contiguous chunks (nwg%8==0)
  const int bm = swv / nbn;                     // bnb-minor within chunk
  const int bnb = swv % nbn;
  const int l15 = lane & 15, l4 = lane >> 4;
  f32x4 acc[4][4] = {};

  const int r0 = tid >> 2, k40 = tid & 3;
  const int k4s = k40 ^ ((r0 >> 1) & 3);
  const size_t aA0 = (size_t)(bm * 128 + r0) * 1536 + k4s * 16;
  const size_t aA1 = (size_t)(bm * 128 + r0 + 64) * 1536 + k4s * 16;
  const size_t aB0 = (size_t)(bnb * 128 + r0) * 1536 + k4s * 16;
  const size_t aB1 = (size_t)(bnb * 128 + r0 + 64) * 1536 + k4s * 16;
  const int dc0 = tid * 16, dc1 = dc0 + 4096;
  const char* Ab = (const char*)A;
  const char* Wb = (const char*)W;

#define STAGE(T64, Q) do { \
    gload_lds16(Ab + aA0 + (T64), L + (Q) * 16384 + dc0); \
    gload_lds16(Ab + aA1 + (T64), L + (Q) * 16384 + dc1); \
    gload_lds16(Wb + aB0 + (T64), L + (Q) * 16384 + 8192 + dc0); \
    gload_lds16(Wb + aB1 + (T64), L + (Q) * 16384 + 8192 + dc1); \
  } while (0)

  int obA[4], obB[4];
#pragma unroll
  for (int i = 0; i < 4; i++) {
    int rowA = wr * 64 + i * 16 + l15;
    obA[i] = rowA * 64 + ((l4 ^ ((rowA >> 1) & 3)) * 16);
    int rowB = wc * 64 + i * 16 + l15;
    obB[i] = 8192 + rowB * 64 + ((l4 ^ ((rowB >> 1) & 3)) * 16);
  }

  STAGE(0, 0); STAGE(64, 1); STAGE(128, 2);
  asm volatile("s_waitcnt vmcnt(8)" ::: "memory");
  __builtin_amdgcn_sched_barrier(0);
  __builtin_amdgcn_s_barrier();
  __builtin_amdgcn_sched_barrier(0);

#pragma unroll
  for (int to = 0; to < 6; ++to) {
#pragma unroll
    for (int ti = 0; ti < 4; ++ti) {
      const int t = to * 4 + ti;
      const int tn = (t + 3 < 24) ? (t + 3) : 23;
      STAGE(tn * 64, (t + 3) & 3);
      const char* bq = L + (t & 3) * 16384;
      h16x8 am[4], bn[4];
#pragma unroll
      for (int i = 0; i < 4; i++) am[i] = *reinterpret_cast<const h16x8*>(bq + obA[i]);
#pragma unroll
      for (int j = 0; j < 4; j++) bn[j] = *reinterpret_cast<const h16x8*>(bq + obB[j]);
      __builtin_amdgcn_s_setprio(1);
#pragma unroll
      for (int i = 0; i < 4; i++)
#pragma unroll
        for (int j = 0; j < 4; j++)
          acc[i][j] = __builtin_amdgcn_mfma_f32_16x16x32_f16(am[i], bn[j], acc[i][j], 0, 0, 0);
      __builtin_amdgcn_s_setprio(0);
      asm volatile("s_waitcnt vmcnt(8)" ::: "memory");
      __builtin_amdgcn_sched_barrier(0);
      __builtin_amdgcn_s_barrier();
      __builtin_amdgcn_sched_barrier(0);
    }
  }
#undef STAGE
  asm volatile("s_waitcnt vmcnt(0)" ::: "memory");

  if (VT && bnb >= 12) {
    // V columns -> transposed vt[((b*NH+h)*64+d)*512 + s]; r -> s consecutive => ushort4 store
#pragma unroll
    for (int i = 0; i < 4; i++) {
      int row0 = bm * 128 + wr * 64 + i * 16 + l4 * 4;
      int b = row0 >> 9, s0 = row0 & 511;
#pragma unroll
      for (int j = 0; j < 4; j++) {
        int vcol = bnb * 128 + wc * 64 + j * 16 + l15 - 1536;
        int hh = vcol >> 6, dd = vcol & 63;
        u16* dst = vt + (((size_t)(b * NH + hh) * 64 + dd) << 9) + s0;
        ushort4 o;
        o.x = f2h(acc[i][j][0]); o.y = f2h(acc[i][j][1]);
        o.z = f2h(acc[i][j][2]); o.w = f2h(acc[i][j][3]);
        *reinterpret_cast<ushort4*>(dst) = o;
      }
    }
    return;
  }

  if (ROPE && bnb < 12) {
#pragma unroll
    for (int i = 0; i < 4; i++) {
      int row0 = bm * 128 + wr * 64 + i * 16 + l4 * 4;
#pragma unroll
      for (int r = 0; r < 4; r++) {
        int pos = pids[row0 + r];
        const float* tb = tab + pos * 64;
#pragma unroll
        for (int j = 0; j < 2; j++) {
          float2 cs = *reinterpret_cast<const float2*>(tb + 2 * (j * 16 + l15));
          float x1 = acc[i][j][r], x2 = acc[i][j + 2][r];
          acc[i][j][r]     = x1 * cs.x - x2 * cs.y;
          acc[i][j + 2][r] = x2 * cs.x + x1 * cs.y;
        }
      }
    }
  }
#pragma unroll
  for (int i = 0; i < 4; i++) {
    int row0 = bm * 128 + wr * 64 + i * 16 + l4 * 4;
#pragma unroll
    for (int j = 0; j < 4; j++) {
      int col = bnb * 128 + wc * 64 + j * 16 + l15;
#pragma unroll
      for (int r = 0; r < 4; r++) {
        int rr = row0 + r;
        int orow = (PERM == 0) ? rr : (PERM == 1) ? ((rr & 511) * 16 + (rr >> 9))
                                                  : ((rr & 15) * 512 + (rr >> 4));
        size_t idx = (size_t)orow * N + col;
        float v = acc[i][j][r];
        if (CMODE == 0)      ((u16*)C)[idx] = f2h(v);
        else if (CMODE == 1) ((u16*)C)[idx] = f2h(v + ((const float*)resid)[idx]);
        else                 ((float*)C)[idx] = v + h2f(((const u16*)resid)[idx]);
      }
    }
  }
}

// ---------------- Pass-1 attention: KVBLK=128, dbuf prefetch, gload_lds K + V^T ----------------
__global__ __launch_bounds__(256) void attn1_k(const u16* __restrict__ qkv, const u16* __restrict__ vt,
                                               u16* __restrict__ O) {
  __shared__ __align__(16) char L[2][32768];   // [buf][ K 16KB | Vt 16KB ]
  __shared__ __align__(16) char Pl[4][4096];   // per-wave P [16 q][128 keys] swizzled
  const int qt = blockIdx.x;   // 0..7
  const int bh = blockIdx.y;   // 0..191
  const int b = bh / NH, h = bh % NH;
  const int tid = threadIdx.x, w = tid >> 6, lane = tid & 63;
  const int l15 = lane & 15, l4 = lane >> 4;
  const size_t qoff = ((size_t)(b * SQ + qt * 64 + w * 16 + l15)) * QKVN + h * 64;
  h16x8 qf[2];
  qf[0] = *reinterpret_cast<const h16x8*>(qkv + qoff + 8 * l4);
  qf[1] = *reinterpret_cast<const h16x8*>(qkv + qoff + 32 + 8 * l4);
  f32x4 acco[4] = {};
  float mrun[4] = {-3e38f, -3e38f, -3e38f, -3e38f};
  float lrun[4] = {0.f, 0.f, 0.f, 0.f};
  const int qrow = qt * 64 + w * 16 + l4 * 4;  // + r
  const int nkt = (qt >> 1) + 1;

  const u16* Kg = qkv + (size_t)b * SQ * QKVN + DM + h * 64;   // + key*QKVN
  const int rK0 = tid >> 3;
  const size_t aK0 = (size_t)rK0 * QKVN + (size_t)(((tid & 7) ^ (rK0 & 7)) * 8);
  const u16* Vg = vt + (size_t)bh * 64 * SQ;                   // + d*SQ
  const int dV0 = tid >> 4;
  const size_t aV0 = (size_t)dV0 * SQ + (size_t)(((tid & 15) ^ (dV0 & 15)) * 8);
  const int dst0 = tid * 16;

#define STAGE1(KT, BUF) do { \
    _Pragma("unroll") \
    for (int e = 0; e < 4; e++) \
      gload_lds16(Kg + aK0 + (size_t)e * (32 * QKVN) + (size_t)(KT) * (128 * QKVN), \
                  L[BUF] + dst0 + e * 4096); \
    _Pragma("unroll") \
    for (int e = 0; e < 4; e++) \
      gload_lds16(Vg + aV0 + e * (16 * SQ) + (KT) * 128, \
                  L[BUF] + 16384 + dst0 + e * 4096); \
  } while (0)

  STAGE1(0, 0);
  asm volatile("s_waitcnt vmcnt(0)" ::: "memory");
  __builtin_amdgcn_sched_barrier(0);
  __builtin_amdgcn_s_barrier();
  __builtin_amdgcn_sched_barrier(0);

  for (int kt = 0; kt < nkt; ++kt) {
    const int cur = kt & 1;
    if (kt + 1 < nkt) STAGE1(kt + 1, cur ^ 1);
    const char* Kb = L[cur];
    const char* Vb = L[cur] + 16384;
    f32x4 sc[8] = {};
    __builtin_amdgcn_s_setprio(1);
#pragma unroll
    for (int kk = 0; kk < 2; kk++) {
#pragma unroll
      for (int j = 0; j < 8; j++) {
        int row = j * 16 + l15;
        int off = row * 128 + (((kk * 4 + l4) ^ (row & 7)) * 16);
        h16x8 kf = *reinterpret_cast<const h16x8*>(Kb + off);
        sc[j] = __builtin_amdgcn_mfma_f32_16x16x32_f16(qf[kk], kf, sc[j], 0, 0, 0);
      }
    }
    __builtin_amdgcn_s_setprio(0);
    float pv[8][4];
#pragma unroll
    for (int j = 0; j < 8; j++)
#pragma unroll
      for (int r = 0; r < 4; r++) pv[j][r] = sc[j][r];
    if (kt == nkt - 1) {  // tile containing the causal diagonal
#pragma unroll
      for (int r = 0; r < 4; r++) {
        int q = qrow + r;
#pragma unroll
        for (int j = 0; j < 8; j++) {
          int key = kt * 128 + j * 16 + l15;
          if (key > q) pv[j][r] = -1e30f;
        }
      }
    }
    float al[4];
#pragma unroll
    for (int r = 0; r < 4; r++) {
      float t0 = fmaxf(fmaxf(pv[0][r], pv[1][r]), fmaxf(pv[2][r], pv[3][r]));
      float t1 = fmaxf(fmaxf(pv[4][r], pv[5][r]), fmaxf(pv[6][r], pv[7][r]));
      float tm = fmaxf(t0, t1);
      tm = fmaxf(tm, __shfl_xor(tm, 1)); tm = fmaxf(tm, __shfl_xor(tm, 2));
      tm = fmaxf(tm, __shfl_xor(tm, 4)); tm = fmaxf(tm, __shfl_xor(tm, 8));
      float mn = fmaxf(mrun[r], tm);
      al[r] = __expf(mrun[r] - mn);
      mrun[r] = mn;
      float ts = 0.f;
#pragma unroll
      for (int j = 0; j < 8; j++) { float p = __expf(pv[j][r] - mn); pv[j][r] = p; ts += p; }
      ts += __shfl_xor(ts, 1); ts += __shfl_xor(ts, 2); ts += __shfl_xor(ts, 4); ts += __shfl_xor(ts, 8);
      lrun[r] = lrun[r] * al[r] + ts;
    }
#pragma unroll
    for (int j = 0; j < 4; j++)
#pragma unroll
      for (int r = 0; r < 4; r++) acco[j][r] *= al[r];
    char* pw = Pl[w];
#pragma unroll
    for (int r = 0; r < 4; r++) {
      int q = l4 * 4 + r;
#pragma unroll
      for (int j = 0; j < 8; j++) {
        int cw = j * 2 + (l15 >> 3);
        int byte = q * 256 + ((cw ^ (q & 15)) * 16) + (l15 & 7) * 2;
        *(u16*)(pw + byte) = f2h(pv[j][r]);
      }
    }
    asm volatile("s_waitcnt lgkmcnt(0)" ::: "memory");
    __builtin_amdgcn_sched_barrier(0);
    __builtin_amdgcn_s_setprio(1);
#pragma unroll
    for (int kk = 0; kk < 4; kk++) {
      h16x8 pa = *reinterpret_cast<const h16x8*>(pw + l15 * 256 + (((kk * 4 + l4) ^ l15) * 16));
#pragma unroll
      for (int j = 0; j < 4; j++) {
        int d = j * 16 + l15;
        int voff = d * 256 + (((kk * 4 + l4) ^ (d & 15)) * 16);
        h16x8 vf = *reinterpret_cast<const h16x8*>(Vb + voff);
        acco[j] = __builtin_amdgcn_mfma_f32_16x16x32_f16(pa, vf, acco[j], 0, 0, 0);
      }
    }
    __builtin_amdgcn_s_setprio(0);
    asm volatile("s_waitcnt vmcnt(0)" ::: "memory");
    __builtin_amdgcn_sched_barrier(0);
    __builtin_amdgcn_s_barrier();
    __builtin_amdgcn_sched_barrier(0);
  }
#undef STAGE1
#pragma unroll
  for (int r = 0; r < 4; r++) {
    float inv = 1.f / lrun[r];
    size_t orow = ((size_t)(b * SQ + qrow + r)) * DM + h * 64;
#pragma unroll
    for (int j = 0; j < 4; j++) O[orow + j * 16 + l15] = f2h(acco[j][r] * inv);
  }
}

// ---------------- Pass-2 attention: 16x16 per (s,h), one wave each (s-major qkv) ----------------
__global__ __launch_bounds__(256) void attn2_k(const u16* __restrict__ qkv, const float* __restrict__ gmask,
                                               u16* __restrict__ O) {
  __shared__ float Pl[4][16][16];
  __shared__ float Vl[4][16][68];
  const int tid = threadIdx.x, w = tid >> 6, lane = tid & 63;
  const int idx = blockIdx.x * 4 + w;
  const int s = idx / NH, h = idx % NH;
  const int l15 = lane & 15, l4 = lane >> 4;
  const size_t base = ((size_t)(s * 16 + l15)) * QKVN + h * 64;
  h16x8 qf0 = *reinterpret_cast<const h16x8*>(qkv + base + 8 * l4);
  h16x8 qf1 = *reinterpret_cast<const h16x8*>(qkv + base + 32 + 8 * l4);
  h16x8 kf0 = *reinterpret_cast<const h16x8*>(qkv + base + DM + 8 * l4);
  h16x8 kf1 = *reinterpret_cast<const h16x8*>(qkv + base + DM + 32 + 8 * l4);
  f32x4 sc = {};
  sc = __builtin_amdgcn_mfma_f32_16x16x32_f16(qf0, kf0, sc, 0, 0, 0);
  sc = __builtin_amdgcn_mfma_f32_16x16x32_f16(qf1, kf1, sc, 0, 0, 0);
  {
    int key = lane >> 2, d0 = (lane & 3) * 16;
    const u16* vsrc = qkv + ((size_t)(s * 16 + key)) * QKVN + 2 * DM + h * 64 + d0;
#pragma unroll
    for (int i = 0; i < 16; i += 4) {
      ushort4 vv = *reinterpret_cast<const ushort4*>(vsrc + i);
      Vl[w][key][d0 + i + 0] = h2f(vv.x);
      Vl[w][key][d0 + i + 1] = h2f(vv.y);
      Vl[w][key][d0 + i + 2] = h2f(vv.z);
      Vl[w][key][d0 + i + 3] = h2f(vv.w);
    }
  }
  const float* gm = gmask + ((size_t)s * NH + h) * 256;
#pragma unroll
  for (int r = 0; r < 4; r++) {
    float v = sc[r] + gm[(l4 * 4 + r) * 16 + l15];
    float mx = v;
    mx = fmaxf(mx, __shfl_xor(mx, 1)); mx = fmaxf(mx, __shfl_xor(mx, 2));
    mx = fmaxf(mx, __shfl_xor(mx, 4)); mx = fmaxf(mx, __shfl_xor(mx, 8));
    float p = __expf(v - mx);
    float su = p;
    su += __shfl_xor(su, 1); su += __shfl_xor(su, 2); su += __shfl_xor(su, 4); su += __shfl_xor(su, 8);
    Pl[w][l4 * 4 + r][l15] = p / su;
  }
  asm volatile("s_waitcnt lgkmcnt(0)" ::: "memory");
  __builtin_amdgcn_sched_barrier(0);
  const int q = lane >> 2, d0 = (lane & 3) * 16;
  float o[16] = {};
#pragma unroll
  for (int key = 0; key < 16; key++) {
    float pp = Pl[w][q][key];
#pragma unroll
    for (int dd = 0; dd < 16; dd += 4) {
      float4 vv = *reinterpret_cast<const float4*>(&Vl[w][key][d0 + dd]);
      o[dd + 0] += pp * vv.x; o[dd + 1] += pp * vv.y; o[dd + 2] += pp * vv.z; o[dd + 3] += pp * vv.w;
    }
  }
  u16* orow = O + ((size_t)(s * 16 + q)) * DM + h * 64 + d0;
#pragma unroll
  for (int i = 0; i < 16; i += 4) {
    ushort4 ov;
    ov.x = f2h(o[i]); ov.y = f2h(o[i + 1]); ov.z = f2h(o[i + 2]); ov.w = f2h(o[i + 3]);
    *reinterpret_cast<ushort4*>(orow + i) = ov;
  }
}

// ---------------- launch ----------------
extern "C" void kernel_launch(void* const* d_in, const int* in_sizes, int n_in,
                              void* d_out, int out_size, void* d_ws, size_t ws_size,
                              hipStream_t stream) {
  const float* hidden = (const float*)d_in[0];
  const int*   pids   = (const int*)d_in[1];
  const float* gmask  = (const float*)d_in[3];
  const float* tq = (const float*)d_in[4];
  const float* tk = (const float*)d_in[5];
  const float* tv = (const float*)d_in[6];
  const float* to_ = (const float*)d_in[7];
  const float* tnw = (const float*)d_in[8];
  const float* gq = (const float*)d_in[9];
  const float* gk = (const float*)d_in[10];
  const float* gv = (const float*)d_in[11];
  const float* go = (const float*)d_in[12];
  const float* gnw = (const float*)d_in[13];
  const float* invf = (const float*)d_in[14];
  float* out = (float*)d_out;
  char* ws = (char*)d_ws;

  u16*   wq1    = (u16*)(ws);                   // 2304x768 fp16
  u16*   wo1    = (u16*)(ws + 3538944);         // 768x768
  u16*   wq2    = (u16*)(ws + 4718592);
  u16*   wo2    = (u16*)(ws + 8257536);
  float* tab    = (float*)(ws + 9437184);       // 512x32x2 f32
  u16*   normed = (u16*)(ws + 9568256);         // 8192x768 fp16
  u16*   obuf   = (u16*)(ws + 22151168);        // 8192x768 fp16
  u16*   h1     = (u16*)(ws + 34734080);        // 8192x768 fp16 residual spine
  u16*   qkv    = (u16*)(ws + 59899904);        // 8192x2304 fp16
  u16*   vt     = (u16*)(ws + 97648640);        // 192 x 64 x 512 fp16 (12.6 MB)

  const int WN = 768 * 768;
  WPtrs P;
  P.s[0] = tq;  P.d[0] = wq1;
  P.s[1] = tk;  P.d[1] = wq1 + WN;
  P.s[2] = tv;  P.d[2] = wq1 + 2 * WN;
  P.s[3] = to_; P.d[3] = wo1;
  P.s[4] = gq;  P.d[4] = wq2;
  P.s[5] = gk;  P.d[5] = wq2 + WN;
  P.s[6] = gv;  P.d[6] = wq2 + 2 * WN;
  P.s[7] = go;  P.d[7] = wo2;

  // pass 1 (time attention, causal + fused RoPE; V written transposed by GEMM epilogue)
  prep_k<<<6720, 256, 0, stream>>>(P, invf, tab, hidden, tnw, normed);
  gemm_k<0, true, 0, true><<<dim3(64, 18), 256, 0, stream>>>(normed, wq1, QKVN, qkv, nullptr, pids, tab, vt);
  attn1_k<<<dim3(8, 192), 256, 0, stream>>>(qkv, vt, obuf);
  gemm_k<1, false, 0, false><<<dim3(64, 6), 256, 0, stream>>>(obuf, wo1, DM, h1, hidden, nullptr, nullptr, nullptr);

  // pass 2 (group attention over batch dim; s-major token order)
  rms_k<<<2048, 256, 0, stream>>>(h1, gnw, normed);
  gemm_k<0, false, 1, false><<<dim3(64, 18), 256, 0, stream>>>(normed, wq2, QKVN, qkv, nullptr, nullptr, nullptr, nullptr);
  attn2_k<<<1536, 256, 0, stream>>>(qkv, gmask, obuf);
  gemm_k<2, false, 2, false><<<dim3(64, 6), 256, 0, stream>>>(obuf, wo2, DM, out, h1, nullptr, nullptr, nullptr);
}

// Round 8
// 206.344 us; speedup vs baseline: 1.2931x; 1.0114x over previous
//
#include <hip/hip_runtime.h>

#define DM   768
#define QKVN 2304
#define SQ   512
#define NB   16
#define NH   12

typedef unsigned short u16;
typedef _Float16 h16;
typedef _Float16 h16x8 __attribute__((ext_vector_type(8)));
typedef float f32x4 __attribute__((ext_vector_type(4)));

__device__ __forceinline__ u16 f2h(float f) {
  h16 h = (h16)f;
  return __builtin_bit_cast(u16, h);
}
__device__ __forceinline__ float h2f(u16 u) {
  return (float)__builtin_bit_cast(h16, u);
}
__device__ __forceinline__ void gload_lds16(const void* g, void* l) {
  __builtin_amdgcn_global_load_lds((__attribute__((address_space(1))) void*)(g),
                                   (__attribute__((address_space(3))) void*)(l), 16, 0, 0);
}

// ---------------- prep: 8x weight convert  U  rope table  U  pass-1 RMSNorm ----------------
struct WPtrs { const float* s[8]; u16* d[8]; };
__global__ __launch_bounds__(256) void prep_k(WPtrs P, const float* __restrict__ invf,
                                              float* __restrict__ tab,
                                              const float* __restrict__ x, const float* __restrict__ nw,
                                              u16* __restrict__ normed) {
  const int bid = blockIdx.x, tid = threadIdx.x;
  if (bid < 4608) {            // weight convert: 8 x 768x768
    int w = bid / 576;
    int i = ((bid % 576) * 256 + tid) * 4;
    float4 v = *reinterpret_cast<const float4*>(P.s[w] + i);
    ushort4 o;
    o.x = f2h(v.x); o.y = f2h(v.y); o.z = f2h(v.z); o.w = f2h(v.w);
    *reinterpret_cast<ushort4*>(P.d[w] + i) = o;
  } else if (bid < 4672) {     // rope table
    int i = (bid - 4608) * 256 + tid;   // 0..16383
    int pos = i >> 5, j = i & 31;
    float a = (float)pos * invf[j];
    float s, c;
    sincosf(a, &s, &c);
    tab[i * 2] = c; tab[i * 2 + 1] = s;
  } else {                     // RMSNorm pass 1: one wave per token
    int wv = tid >> 6, lane = tid & 63;
    size_t t = (size_t)(bid - 4672) * 4 + wv;
    const float* row = x + t * DM;
    float4 v[3];
    float ss = 0.f;
#pragma unroll
    for (int i = 0; i < 3; i++) {
      v[i] = *reinterpret_cast<const float4*>(row + (lane + 64 * i) * 4);
      ss += v[i].x * v[i].x + v[i].y * v[i].y + v[i].z * v[i].z + v[i].w * v[i].w;
    }
#pragma unroll
    for (int d = 1; d < 64; d <<= 1) ss += __shfl_xor(ss, d);
    float rs = rsqrtf(ss * (1.0f / 768.f) + 1e-6f);
    u16* orow = normed + t * DM;
#pragma unroll
    for (int i = 0; i < 3; i++) {
      int c = (lane + 64 * i) * 4;
      float4 wv4 = *reinterpret_cast<const float4*>(nw + c);
      ushort4 o;
      o.x = f2h(v[i].x * rs * wv4.x);
      o.y = f2h(v[i].y * rs * wv4.y);
      o.z = f2h(v[i].z * rs * wv4.z);
      o.w = f2h(v[i].w * rs * wv4.w);
      *reinterpret_cast<ushort4*>(orow + c) = o;
    }
  }
}

// ---------------- RMSNorm pass 2: fp16 input (h1) ----------------
__global__ __launch_bounds__(256) void rms_k(const u16* __restrict__ x, const float* __restrict__ w,
                                             u16* __restrict__ out) {
  int wv = threadIdx.x >> 6, lane = threadIdx.x & 63;
  size_t t = (size_t)blockIdx.x * 4 + wv;
  const u16* row = x + t * DM;
  float4 v[3];
  float ss = 0.f;
#pragma unroll
  for (int i = 0; i < 3; i++) {
    ushort4 rw = *reinterpret_cast<const ushort4*>(row + (lane + 64 * i) * 4);
    v[i].x = h2f(rw.x); v[i].y = h2f(rw.y); v[i].z = h2f(rw.z); v[i].w = h2f(rw.w);
    ss += v[i].x * v[i].x + v[i].y * v[i].y + v[i].z * v[i].z + v[i].w * v[i].w;
  }
#pragma unroll
  for (int d = 1; d < 64; d <<= 1) ss += __shfl_xor(ss, d);
  float rs = rsqrtf(ss * (1.0f / 768.f) + 1e-6f);
  u16* orow = out + t * DM;
#pragma unroll
  for (int i = 0; i < 3; i++) {
    int c = (lane + 64 * i) * 4;
    float4 wv4 = *reinterpret_cast<const float4*>(w + c);
    ushort4 o;
    o.x = f2h(v[i].x * rs * wv4.x);
    o.y = f2h(v[i].y * rs * wv4.y);
    o.z = f2h(v[i].z * rs * wv4.z);
    o.w = f2h(v[i].w * rs * wv4.w);
    *reinterpret_cast<ushort4*>(orow + c) = o;
  }
}

// ---------------- GEMM: C[M=8192,N] = A[M,768] * W[N,768]^T (both fp16, K-major) ----------------
// 128x128 tile, BK=32. Round-8: 3-buffer (48KB LDS) counted-vmcnt(4) pipeline -> 3 blocks/CU
// (was 4-buf/64KB/2 blocks/CU; m132 showed the 2-block occupancy cliff costs ~40%).
// Buffer (t+2)%3 == (t-1)%3 is dead at iter t (drained at t-1's barrier); vmcnt(4) leaves only
// stage(t+2) outstanding => stage(t+1) landed before its reads. XCD chunking bnb-minor (L2-resident).
template <int CMODE, bool ROPE, int PERM, bool VT>
__global__ __launch_bounds__(256, 3) void gemm_k(const u16* __restrict__ A, const u16* __restrict__ W, int N,
                                              void* __restrict__ C, const void* __restrict__ resid,
                                              const int* __restrict__ pids, const float* __restrict__ tab,
                                              u16* __restrict__ vt) {
  __shared__ __align__(16) char L[3 * 16384];   // 3 bufs x (A 8KB + B 8KB)
  const int tid = threadIdx.x, w = tid >> 6, lane = tid & 63;
  const int wr = w >> 1, wc = w & 1;
  const int nbn = gridDim.y;                    // N/128
  int nf = blockIdx.y * gridDim.x + blockIdx.x;
  int nwg = gridDim.x * nbn;
  int swv = (nf & 7) * (nwg >> 3) + (nf >> 3);  // XCD-contiguous chunks (nwg%8==0)
  const int bm = swv / nbn;                     // bnb-minor within chunk
  const int bnb = swv % nbn;
  const int l15 = lane & 15, l4 = lane >> 4;
  f32x4 acc[4][4] = {};

  const int r0 = tid >> 2, k40 = tid & 3;
  const int k4s = k40 ^ ((r0 >> 1) & 3);
  const size_t aA0 = (size_t)(bm * 128 + r0) * 1536 + k4s * 16;
  const size_t aA1 = (size_t)(bm * 128 + r0 + 64) * 1536 + k4s * 16;
  const size_t aB0 = (size_t)(bnb * 128 + r0) * 1536 + k4s * 16;
  const size_t aB1 = (size_t)(bnb * 128 + r0 + 64) * 1536 + k4s * 16;
  const int dc0 = tid * 16, dc1 = dc0 + 4096;
  const char* Ab = (const char*)A;
  const char* Wb = (const char*)W;

#define STAGE(T64, Q) do { \
    gload_lds16(Ab + aA0 + (T64), L + (Q) * 16384 + dc0); \
    gload_lds16(Ab + aA1 + (T64), L + (Q) * 16384 + dc1); \
    gload_lds16(Wb + aB0 + (T64), L + (Q) * 16384 + 8192 + dc0); \
    gload_lds16(Wb + aB1 + (T64), L + (Q) * 16384 + 8192 + dc1); \
  } while (0)

  int obA[4], obB[4];
#pragma unroll
  for (int i = 0; i < 4; i++) {
    int rowA = wr * 64 + i * 16 + l15;
    obA[i] = rowA * 64 + ((l4 ^ ((rowA >> 1) & 3)) * 16);
    int rowB = wc * 64 + i * 16 + l15;
    obB[i] = 8192 + rowB * 64 + ((l4 ^ ((rowB >> 1) & 3)) * 16);
  }

  // prologue: stage tiles 0,1; wait stage0 (8 outstanding -> 4)
  STAGE(0, 0); STAGE(64, 1);
  asm volatile("s_waitcnt vmcnt(4)" ::: "memory");
  __builtin_amdgcn_sched_barrier(0);
  __builtin_amdgcn_s_barrier();
  __builtin_amdgcn_sched_barrier(0);

#pragma unroll
  for (int to = 0; to < 8; ++to) {
#pragma unroll
    for (int ti = 0; ti < 3; ++ti) {
      const int t = to * 3 + ti;
      const int tn = (t + 2 < 24) ? (t + 2) : 23;     // tail: dummy re-stage of tile 23
      STAGE(tn * 64, (t + 2) % 3);                    // dest buffer (t-1)%3 is dead
      const char* bq = L + (t % 3) * 16384;
      h16x8 am[4], bn[4];
#pragma unroll
      for (int i = 0; i < 4; i++) am[i] = *reinterpret_cast<const h16x8*>(bq + obA[i]);
#pragma unroll
      for (int j = 0; j < 4; j++) bn[j] = *reinterpret_cast<const h16x8*>(bq + obB[j]);
      __builtin_amdgcn_s_setprio(1);
#pragma unroll
      for (int i = 0; i < 4; i++)
#pragma unroll
        for (int j = 0; j < 4; j++)
          acc[i][j] = __builtin_amdgcn_mfma_f32_16x16x32_f16(am[i], bn[j], acc[i][j], 0, 0, 0);
      __builtin_amdgcn_s_setprio(0);
      asm volatile("s_waitcnt vmcnt(4)" ::: "memory");
      __builtin_amdgcn_sched_barrier(0);
      __builtin_amdgcn_s_barrier();
      __builtin_amdgcn_sched_barrier(0);
    }
  }
#undef STAGE
  asm volatile("s_waitcnt vmcnt(0)" ::: "memory");   // drain dummy stages before exit

  if (VT && bnb >= 12) {
    // V columns -> transposed vt[((b*NH+h)*64+d)*512 + s]; r -> s consecutive => ushort4 store
#pragma unroll
    for (int i = 0; i < 4; i++) {
      int row0 = bm * 128 + wr * 64 + i * 16 + l4 * 4;
      int b = row0 >> 9, s0 = row0 & 511;
#pragma unroll
      for (int j = 0; j < 4; j++) {
        int vcol = bnb * 128 + wc * 64 + j * 16 + l15 - 1536;
        int hh = vcol >> 6, dd = vcol & 63;
        u16* dst = vt + (((size_t)(b * NH + hh) * 64 + dd) << 9) + s0;
        ushort4 o;
        o.x = f2h(acc[i][j][0]); o.y = f2h(acc[i][j][1]);
        o.z = f2h(acc[i][j][2]); o.w = f2h(acc[i][j][3]);
        *reinterpret_cast<ushort4*>(dst) = o;
      }
    }
    return;
  }

  if (ROPE && bnb < 12) {
#pragma unroll
    for (int i = 0; i < 4; i++) {
      int row0 = bm * 128 + wr * 64 + i * 16 + l4 * 4;
#pragma unroll
      for (int r = 0; r < 4; r++) {
        int pos = pids[row0 + r];
        const float* tb = tab + pos * 64;
#pragma unroll
        for (int j = 0; j < 2; j++) {
          float2 cs = *reinterpret_cast<const float2*>(tb + 2 * (j * 16 + l15));
          float x1 = acc[i][j][r], x2 = acc[i][j + 2][r];
          acc[i][j][r]     = x1 * cs.x - x2 * cs.y;
          acc[i][j + 2][r] = x2 * cs.x + x1 * cs.y;
        }
      }
    }
  }
#pragma unroll
  for (int i = 0; i < 4; i++) {
    int row0 = bm * 128 + wr * 64 + i * 16 + l4 * 4;
#pragma unroll
    for (int j = 0; j < 4; j++) {
      int col = bnb * 128 + wc * 64 + j * 16 + l15;
#pragma unroll
      for (int r = 0; r < 4; r++) {
        int rr = row0 + r;
        int orow = (PERM == 0) ? rr : (PERM == 1) ? ((rr & 511) * 16 + (rr >> 9))
                                                  : ((rr & 15) * 512 + (rr >> 4));
        size_t idx = (size_t)orow * N + col;
        float v = acc[i][j][r];
        if (CMODE == 0)      ((u16*)C)[idx] = f2h(v);
        else if (CMODE == 1) ((u16*)C)[idx] = f2h(v + ((const float*)resid)[idx]);
        else                 ((float*)C)[idx] = v + h2f(((const u16*)resid)[idx]);
      }
    }
  }
}

// ---------------- Pass-1 attention: KVBLK=128, dbuf prefetch, gload_lds K + V^T ----------------
__global__ __launch_bounds__(256) void attn1_k(const u16* __restrict__ qkv, const u16* __restrict__ vt,
                                               u16* __restrict__ O) {
  __shared__ __align__(16) char L[2][32768];   // [buf][ K 16KB | Vt 16KB ]
  __shared__ __align__(16) char Pl[4][4096];   // per-wave P [16 q][128 keys] swizzled
  const int qt = blockIdx.x;   // 0..7
  const int bh = blockIdx.y;   // 0..191
  const int b = bh / NH, h = bh % NH;
  const int tid = threadIdx.x, w = tid >> 6, lane = tid & 63;
  const int l15 = lane & 15, l4 = lane >> 4;
  const size_t qoff = ((size_t)(b * SQ + qt * 64 + w * 16 + l15)) * QKVN + h * 64;
  h16x8 qf[2];
  qf[0] = *reinterpret_cast<const h16x8*>(qkv + qoff + 8 * l4);
  qf[1] = *reinterpret_cast<const h16x8*>(qkv + qoff + 32 + 8 * l4);
  f32x4 acco[4] = {};
  float mrun[4] = {-3e38f, -3e38f, -3e38f, -3e38f};
  float lrun[4] = {0.f, 0.f, 0.f, 0.f};
  const int qrow = qt * 64 + w * 16 + l4 * 4;  // + r
  const int nkt = (qt >> 1) + 1;

  const u16* Kg = qkv + (size_t)b * SQ * QKVN + DM + h * 64;   // + key*QKVN
  const int rK0 = tid >> 3;
  const size_t aK0 = (size_t)rK0 * QKVN + (size_t)(((tid & 7) ^ (rK0 & 7)) * 8);
  const u16* Vg = vt + (size_t)bh * 64 * SQ;                   // + d*SQ
  const int dV0 = tid >> 4;
  const size_t aV0 = (size_t)dV0 * SQ + (size_t)(((tid & 15) ^ (dV0 & 15)) * 8);
  const int dst0 = tid * 16;

#define STAGE1(KT, BUF) do { \
    _Pragma("unroll") \
    for (int e = 0; e < 4; e++) \
      gload_lds16(Kg + aK0 + (size_t)e * (32 * QKVN) + (size_t)(KT) * (128 * QKVN), \
                  L[BUF] + dst0 + e * 4096); \
    _Pragma("unroll") \
    for (int e = 0; e < 4; e++) \
      gload_lds16(Vg + aV0 + e * (16 * SQ) + (KT) * 128, \
                  L[BUF] + 16384 + dst0 + e * 4096); \
  } while (0)

  STAGE1(0, 0);
  asm volatile("s_waitcnt vmcnt(0)" ::: "memory");
  __builtin_amdgcn_sched_barrier(0);
  __builtin_amdgcn_s_barrier();
  __builtin_amdgcn_sched_barrier(0);

  for (int kt = 0; kt < nkt; ++kt) {
    const int cur = kt & 1;
    if (kt + 1 < nkt) STAGE1(kt + 1, cur ^ 1);
    const char* Kb = L[cur];
    const char* Vb = L[cur] + 16384;
    f32x4 sc[8] = {};
    __builtin_amdgcn_s_setprio(1);
#pragma unroll
    for (int kk = 0; kk < 2; kk++) {
#pragma unroll
      for (int j = 0; j < 8; j++) {
        int row = j * 16 + l15;
        int off = row * 128 + (((kk * 4 + l4) ^ (row & 7)) * 16);
        h16x8 kf = *reinterpret_cast<const h16x8*>(Kb + off);
        sc[j] = __builtin_amdgcn_mfma_f32_16x16x32_f16(qf[kk], kf, sc[j], 0, 0, 0);
      }
    }
    __builtin_amdgcn_s_setprio(0);
    float pv[8][4];
#pragma unroll
    for (int j = 0; j < 8; j++)
#pragma unroll
      for (int r = 0; r < 4; r++) pv[j][r] = sc[j][r];
    if (kt == nkt - 1) {  // tile containing the causal diagonal
#pragma unroll
      for (int r = 0; r < 4; r++) {
        int q = qrow + r;
#pragma unroll
        for (int j = 0; j < 8; j++) {
          int key = kt * 128 + j * 16 + l15;
          if (key > q) pv[j][r] = -1e30f;
        }
      }
    }
    float al[4];
#pragma unroll
    for (int r = 0; r < 4; r++) {
      float t0 = fmaxf(fmaxf(pv[0][r], pv[1][r]), fmaxf(pv[2][r], pv[3][r]));
      float t1 = fmaxf(fmaxf(pv[4][r], pv[5][r]), fmaxf(pv[6][r], pv[7][r]));
      float tm = fmaxf(t0, t1);
      tm = fmaxf(tm, __shfl_xor(tm, 1)); tm = fmaxf(tm, __shfl_xor(tm, 2));
      tm = fmaxf(tm, __shfl_xor(tm, 4)); tm = fmaxf(tm, __shfl_xor(tm, 8));
      float mn = fmaxf(mrun[r], tm);
      al[r] = __expf(mrun[r] - mn);
      mrun[r] = mn;
      float ts = 0.f;
#pragma unroll
      for (int j = 0; j < 8; j++) { float p = __expf(pv[j][r] - mn); pv[j][r] = p; ts += p; }
      ts += __shfl_xor(ts, 1); ts += __shfl_xor(ts, 2); ts += __shfl_xor(ts, 4); ts += __shfl_xor(ts, 8);
      lrun[r] = lrun[r] * al[r] + ts;
    }
#pragma unroll
    for (int j = 0; j < 4; j++)
#pragma unroll
      for (int r = 0; r < 4; r++) acco[j][r] *= al[r];
    char* pw = Pl[w];
#pragma unroll
    for (int r = 0; r < 4; r++) {
      int q = l4 * 4 + r;
#pragma unroll
      for (int j = 0; j < 8; j++) {
        int cw = j * 2 + (l15 >> 3);
        int byte = q * 256 + ((cw ^ (q & 15)) * 16) + (l15 & 7) * 2;
        *(u16*)(pw + byte) = f2h(pv[j][r]);
      }
    }
    asm volatile("s_waitcnt lgkmcnt(0)" ::: "memory");
    __builtin_amdgcn_sched_barrier(0);
    __builtin_amdgcn_s_setprio(1);
#pragma unroll
    for (int kk = 0; kk < 4; kk++) {
      h16x8 pa = *reinterpret_cast<const h16x8*>(pw + l15 * 256 + (((kk * 4 + l4) ^ l15) * 16));
#pragma unroll
      for (int j = 0; j < 4; j++) {
        int d = j * 16 + l15;
        int voff = d * 256 + (((kk * 4 + l4) ^ (d & 15)) * 16);
        h16x8 vf = *reinterpret_cast<const h16x8*>(Vb + voff);
        acco[j] = __builtin_amdgcn_mfma_f32_16x16x32_f16(pa, vf, acco[j], 0, 0, 0);
      }
    }
    __builtin_amdgcn_s_setprio(0);
    asm volatile("s_waitcnt vmcnt(0)" ::: "memory");
    __builtin_amdgcn_sched_barrier(0);
    __builtin_amdgcn_s_barrier();
    __builtin_amdgcn_sched_barrier(0);
  }
#undef STAGE1
#pragma unroll
  for (int r = 0; r < 4; r++) {
    float inv = 1.f / lrun[r];
    size_t orow = ((size_t)(b * SQ + qrow + r)) * DM + h * 64;
#pragma unroll
    for (int j = 0; j < 4; j++) O[orow + j * 16 + l15] = f2h(acco[j][r] * inv);
  }
}

// ---------------- Pass-2 attention: 16x16 per (s,h), one wave each (s-major qkv) ----------------
__global__ __launch_bounds__(256) void attn2_k(const u16* __restrict__ qkv, const float* __restrict__ gmask,
                                               u16* __restrict__ O) {
  __shared__ float Pl[4][16][16];
  __shared__ float Vl[4][16][68];
  const int tid = threadIdx.x, w = tid >> 6, lane = tid & 63;
  const int idx = blockIdx.x * 4 + w;
  const int s = idx / NH, h = idx % NH;
  const int l15 = lane & 15, l4 = lane >> 4;
  const size_t base = ((size_t)(s * 16 + l15)) * QKVN + h * 64;
  h16x8 qf0 = *reinterpret_cast<const h16x8*>(qkv + base + 8 * l4);
  h16x8 qf1 = *reinterpret_cast<const h16x8*>(qkv + base + 32 + 8 * l4);
  h16x8 kf0 = *reinterpret_cast<const h16x8*>(qkv + base + DM + 8 * l4);
  h16x8 kf1 = *reinterpret_cast<const h16x8*>(qkv + base + DM + 32 + 8 * l4);
  f32x4 sc = {};
  sc = __builtin_amdgcn_mfma_f32_16x16x32_f16(qf0, kf0, sc, 0, 0, 0);
  sc = __builtin_amdgcn_mfma_f32_16x16x32_f16(qf1, kf1, sc, 0, 0, 0);
  {
    int key = lane >> 2, d0 = (lane & 3) * 16;
    const u16* vsrc = qkv + ((size_t)(s * 16 + key)) * QKVN + 2 * DM + h * 64 + d0;
#pragma unroll
    for (int i = 0; i < 16; i += 4) {
      ushort4 vv = *reinterpret_cast<const ushort4*>(vsrc + i);
      Vl[w][key][d0 + i + 0] = h2f(vv.x);
      Vl[w][key][d0 + i + 1] = h2f(vv.y);
      Vl[w][key][d0 + i + 2] = h2f(vv.z);
      Vl[w][key][d0 + i + 3] = h2f(vv.w);
    }
  }
  const float* gm = gmask + ((size_t)s * NH + h) * 256;
#pragma unroll
  for (int r = 0; r < 4; r++) {
    float v = sc[r] + gm[(l4 * 4 + r) * 16 + l15];
    float mx = v;
    mx = fmaxf(mx, __shfl_xor(mx, 1)); mx = fmaxf(mx, __shfl_xor(mx, 2));
    mx = fmaxf(mx, __shfl_xor(mx, 4)); mx = fmaxf(mx, __shfl_xor(mx, 8));
    float p = __expf(v - mx);
    float su = p;
    su += __shfl_xor(su, 1); su += __shfl_xor(su, 2); su += __shfl_xor(su, 4); su += __shfl_xor(su, 8);
    Pl[w][l4 * 4 + r][l15] = p / su;
  }
  asm volatile("s_waitcnt lgkmcnt(0)" ::: "memory");
  __builtin_amdgcn_sched_barrier(0);
  const int q = lane >> 2, d0 = (lane & 3) * 16;
  float o[16] = {};
#pragma unroll
  for (int key = 0; key < 16; key++) {
    float pp = Pl[w][q][key];
#pragma unroll
    for (int dd = 0; dd < 16; dd += 4) {
      float4 vv = *reinterpret_cast<const float4*>(&Vl[w][key][d0 + dd]);
      o[dd + 0] += pp * vv.x; o[dd + 1] += pp * vv.y; o[dd + 2] += pp * vv.z; o[dd + 3] += pp * vv.w;
    }
  }
  u16* orow = O + ((size_t)(s * 16 + q)) * DM + h * 64 + d0;
#pragma unroll
  for (int i = 0; i < 16; i += 4) {
    ushort4 ov;
    ov.x = f2h(o[i]); ov.y = f2h(o[i + 1]); ov.z = f2h(o[i + 2]); ov.w = f2h(o[i + 3]);
    *reinterpret_cast<ushort4*>(orow + i) = ov;
  }
}

// ---------------- launch ----------------
extern "C" void kernel_launch(void* const* d_in, const int* in_sizes, int n_in,
                              void* d_out, int out_size, void* d_ws, size_t ws_size,
                              hipStream_t stream) {
  const float* hidden = (const float*)d_in[0];
  const int*   pids   = (const int*)d_in[1];
  const float* gmask  = (const float*)d_in[3];
  const float* tq = (const float*)d_in[4];
  const float* tk = (const float*)d_in[5];
  const float* tv = (const float*)d_in[6];
  const float* to_ = (const float*)d_in[7];
  const float* tnw = (const float*)d_in[8];
  const float* gq = (const float*)d_in[9];
  const float* gk = (const float*)d_in[10];
  const float* gv = (const float*)d_in[11];
  const float* go = (const float*)d_in[12];
  const float* gnw = (const float*)d_in[13];
  const float* invf = (const float*)d_in[14];
  float* out = (float*)d_out;
  char* ws = (char*)d_ws;

  u16*   wq1    = (u16*)(ws);                   // 2304x768 fp16
  u16*   wo1    = (u16*)(ws + 3538944);         // 768x768
  u16*   wq2    = (u16*)(ws + 4718592);
  u16*   wo2    = (u16*)(ws + 8257536);
  float* tab    = (float*)(ws + 9437184);       // 512x32x2 f32
  u16*   normed = (u16*)(ws + 9568256);         // 8192x768 fp16
  u16*   obuf   = (u16*)(ws + 22151168);        // 8192x768 fp16
  u16*   h1     = (u16*)(ws + 34734080);        // 8192x768 fp16 residual spine
  u16*   qkv    = (u16*)(ws + 59899904);        // 8192x2304 fp16
  u16*   vt     = (u16*)(ws + 97648640);        // 192 x 64 x 512 fp16 (12.6 MB)

  const int WN = 768 * 768;
  WPtrs P;
  P.s[0] = tq;  P.d[0] = wq1;
  P.s[1] = tk;  P.d[1] = wq1 + WN;
  P.s[2] = tv;  P.d[2] = wq1 + 2 * WN;
  P.s[3] = to_; P.d[3] = wo1;
  P.s[4] = gq;  P.d[4] = wq2;
  P.s[5] = gk;  P.d[5] = wq2 + WN;
  P.s[6] = gv;  P.d[6] = wq2 + 2 * WN;
  P.s[7] = go;  P.d[7] = wo2;

  // pass 1 (time attention, causal + fused RoPE; V written transposed by GEMM epilogue)
  prep_k<<<6720, 256, 0, stream>>>(P, invf, tab, hidden, tnw, normed);
  gemm_k<0, true, 0, true><<<dim3(64, 18), 256, 0, stream>>>(normed, wq1, QKVN, qkv, nullptr, pids, tab, vt);
  attn1_k<<<dim3(8, 192), 256, 0, stream>>>(qkv, vt, obuf);
  gemm_k<1, false, 0, false><<<dim3(64, 6), 256, 0, stream>>>(obuf, wo1, DM, h1, hidden, nullptr, nullptr, nullptr);

  // pass 2 (group attention over batch dim; s-major token order)
  rms_k<<<2048, 256, 0, stream>>>(h1, gnw, normed);
  gemm_k<0, false, 1, false><<<dim3(64, 18), 256, 0, stream>>>(normed, wq2, QKVN, qkv, nullptr, nullptr, nullptr, nullptr);
  attn2_k<<<1536, 256, 0, stream>>>(qkv, gmask, obuf);
  gemm_k<2, false, 2, false><<<dim3(64, 6), 256, 0, stream>>>(obuf, wo2, DM, out, h1, nullptr, nullptr, nullptr);
}